// Round 9
// baseline (350.309 us; speedup 1.0000x reference)
//
#include <hip/hip_runtime.h>

// ---------------------------------------------------------------------------
// LSTMDecoder: 3 chained LSTM cells + edge FC + 3-head attention + heads.
// B=1024, H=768, S=256, C=(202,183,11).
// R9: K3 (hfc/cfc) eliminated: gates3 = Gpre3 + h1*Whh3^T + h2*W2'^T + b3'
// with W2' = Whh3*hfcW and b3' = Whh3*hfcb precomputed in K1's idle blocks;
// cp3 computed inside cell3 by a sequential mini-pipeline. 7 nodes.
// fp16 MFMA, 4-buffer counted-vmcnt (6/3/0 main, 4/2/0 mini), fused cell
// epilogues, fused coalesced single-pass fp32 attention.
// Whh layout [3,3072,768]: task t base = Whh + t*2359296.
// ---------------------------------------------------------------------------

typedef unsigned short u16;
typedef _Float16       f16x8 __attribute__((ext_vector_type(8)));
typedef float          f32x4 __attribute__((ext_vector_type(4)));

#define SWZ(r) ((((r) + ((r) >> 2))) & 3)
#define VMCNT(N) asm volatile("s_waitcnt vmcnt(" #N ")" ::: "memory")
#define KBAR()  do { __builtin_amdgcn_s_barrier(); __builtin_amdgcn_sched_barrier(0); } while (0)

__device__ __forceinline__ u16 f2h(float f) {
  _Float16 h = (_Float16)f;
  return __builtin_bit_cast(u16, h);
}
__device__ __forceinline__ float sigm(float x) { return 1.f / (1.f + __expf(-x)); }
__device__ __forceinline__ float ftanh(float x) { return 1.f - 2.f / (__expf(2.f * x) + 1.f); }

__device__ __forceinline__ void gld16(const u16* g, u16* l) {
  __builtin_amdgcn_global_load_lds(
      (const __attribute__((address_space(1))) unsigned int*)(g),
      (__attribute__((address_space(3))) unsigned int*)(l),
      16, 0, 0);
}

struct KP { const u16 *pA1, *pA2, *pW1_0, *pW2_0, *pW1_1, *pW2_1; };

__device__ __forceinline__ void stage_tile(const KP& kp, int kt, int ntA,
                                           u16* Asb, u16* Bsb, int wv) {
  const bool s1 = (kt < ntA);
  const int off = (s1 ? kt : kt - ntA) * 32;
  gld16((s1 ? kp.pA1   : kp.pA2  ) + off, Asb + wv * 512);
  gld16((s1 ? kp.pW1_0 : kp.pW2_0) + off, Bsb + wv * 512);
  gld16((s1 ? kp.pW1_1 : kp.pW2_1) + off, Bsb + 2048 + wv * 512);
}

__device__ __forceinline__ void compute_tile(const u16* Asb, const u16* Bsb,
                                             int wv, int frow, int fsl, f32x4* acc) {
  const int ar = wv * 16 + frow;
  f16x8 ah = *(const f16x8*)(Asb + ar * 32 + ((fsl ^ SWZ(ar)) * 8));
  f16x8 bh[8];
#pragma unroll
  for (int n = 0; n < 8; ++n) {
    const int br = n * 16 + frow;
    bh[n] = *(const f16x8*)(Bsb + br * 32 + ((fsl ^ SWZ(br)) * 8));
  }
#pragma unroll
  for (int n = 0; n < 8; ++n)
    acc[n] = __builtin_amdgcn_mfma_f32_16x16x32_f16(ah, bh[n], acc[n], 0, 0, 0);
}

__device__ __forceinline__ void kloop4(const KP& kp, int ntA, int NT,
                                       u16* As, u16* Bs,
                                       int wv, int frow, int fsl, f32x4* acc) {
  stage_tile(kp, 0, ntA, As,        Bs,        wv);
  stage_tile(kp, 1, ntA, As + 2048, Bs + 4096, wv);
  stage_tile(kp, 2, ntA, As + 4096, Bs + 8192, wv);
  for (int t = 0; t < NT - 2; ++t) {
    VMCNT(6); KBAR();
    const int cb = t & 3;
    compute_tile(As + cb * 2048, Bs + cb * 4096, wv, frow, fsl, acc);
    if (t + 3 < NT) {
      const int sb = (t + 3) & 3;
      stage_tile(kp, t + 3, ntA, As + sb * 2048, Bs + sb * 4096, wv);
    }
  }
  VMCNT(3); KBAR();
  compute_tile(As + ((NT - 2) & 3) * 2048, Bs + ((NT - 2) & 3) * 4096,
               wv, frow, fsl, acc);
  VMCNT(0); KBAR();
  compute_tile(As + ((NT - 1) & 3) * 2048, Bs + ((NT - 1) & 3) * 4096,
               wv, frow, fsl, acc);
}

// ---------------------------------------------------------------------------
struct GJob {
  const u16* A; const u16* W;
  float* outf; u16* outh;
  const float* bias; const float* bias2; const float* addend;
  int N; int ldc; int relu;
};

__device__ __forceinline__ void run_gemm(const GJob& jb, int bx, int by,
                                         u16* As, u16* Bs, int tid) {
  const int bn0 = bx * 128;
  if (bn0 >= jb.N) return;
  const int bm0 = by * 64;
  const int lane = tid & 63, wv = tid >> 6;
  const int frow = lane & 15, fsl = lane >> 4;

  const int ra  = tid >> 2,        csa  = (tid & 3) ^ SWZ(ra);
  const int rb1 = (tid >> 2) + 64, csb1 = (tid & 3) ^ SWZ(rb1);
  int wr0 = bn0 + ra;  if (wr0 >= jb.N) wr0 = jb.N - 1;
  int wr1 = bn0 + rb1; if (wr1 >= jb.N) wr1 = jb.N - 1;

  KP kp;
  kp.pA1 = kp.pA2 = jb.A + (size_t)(bm0 + ra) * 768 + csa * 8;
  kp.pW1_0 = kp.pW2_0 = jb.W + (size_t)wr0 * 768 + csa * 8;
  kp.pW1_1 = kp.pW2_1 = jb.W + (size_t)wr1 * 768 + csb1 * 8;

  f32x4 acc[8];
#pragma unroll
  for (int n = 0; n < 8; ++n) acc[n] = (f32x4){0.f, 0.f, 0.f, 0.f};

  kloop4(kp, 24, 24, As, Bs, wv, frow, fsl, acc);

  const int rb = (lane >> 4) * 4;
  const int cc = lane & 15;
#pragma unroll
  for (int n = 0; n < 8; ++n) {
    const int col = bn0 + n * 16 + cc;
    if (col >= jb.N) continue;
    float bv = 0.f;
    if (jb.bias)  bv += jb.bias[col];
    if (jb.bias2) bv += jb.bias2[col];
    const int row0 = bm0 + wv * 16 + rb;
#pragma unroll
    for (int r = 0; r < 4; ++r) {
      const int row = row0 + r;
      float v = acc[n][r] + bv;
      if (jb.addend) v += jb.addend[(size_t)row * jb.ldc + col];
      if (jb.relu)   v = fmaxf(v, 0.f);
      if (jb.outf)   jb.outf[(size_t)row * jb.ldc + col] = v;
      if (jb.outh)   jb.outh[(size_t)row * jb.ldc + col] = f2h(v);
    }
  }
}

__device__ __forceinline__ void run_cell(const u16* A, const u16* W,
                                         const float* bi, const float* bh_,
                                         const float* addend,
                                         const float* cprev,
                                         float* hf, float* cf, u16* hh, u16* ch,
                                         int bx, int by,
                                         u16* As, u16* Bs, int tid) {
  const int bj0 = bx * 32;
  const int bm0 = by * 64;
  const int lane = tid & 63, wv = tid >> 6;
  const int frow = lane & 15, fsl = lane >> 4;

  const int ra  = tid >> 2,        csa  = (tid & 3) ^ SWZ(ra);
  const int rb1 = (tid >> 2) + 64, csb1 = (tid & 3) ^ SWZ(rb1);
  const int wr0 = (ra >> 5) * 768 + bj0 + (ra & 31);
  const int wr1 = (rb1 >> 5) * 768 + bj0 + (rb1 & 31);

  KP kp;
  kp.pA1 = kp.pA2 = A + (size_t)(bm0 + ra) * 768 + csa * 8;
  kp.pW1_0 = kp.pW2_0 = W + (size_t)wr0 * 768 + csa * 8;
  kp.pW1_1 = kp.pW2_1 = W + (size_t)wr1 * 768 + csb1 * 8;

  f32x4 acc[8];
#pragma unroll
  for (int n = 0; n < 8; ++n) acc[n] = (f32x4){0.f, 0.f, 0.f, 0.f};

  kloop4(kp, 24, 24, As, Bs, wv, frow, fsl, acc);

  const int rb = (lane >> 4) * 4;
  const int cc = lane & 15;
#pragma unroll
  for (int jj = 0; jj < 2; ++jj) {
    const int j = bj0 + jj * 16 + cc;
    float b_i = 0.f, b_f = 0.f, b_g = 0.f, b_o = 0.f;
    if (bi) {
      b_i = bi[j]        + bh_[j];
      b_f = bi[768 + j]  + bh_[768 + j];
      b_g = bi[1536 + j] + bh_[1536 + j];
      b_o = bi[2304 + j] + bh_[2304 + j];
    }
    const int row0 = bm0 + wv * 16 + rb;
#pragma unroll
    for (int r = 0; r < 4; ++r) {
      const int row = row0 + r;
      float gi = acc[0 + jj][r] + b_i;
      float gf = acc[2 + jj][r] + b_f;
      float gg = acc[4 + jj][r] + b_g;
      float go = acc[6 + jj][r] + b_o;
      if (addend) {
        const float* ad = addend + (size_t)row * 6144;
        gi += ad[j]; gf += ad[768 + j]; gg += ad[1536 + j]; go += ad[2304 + j];
      }
      float c = sigm(gi) * ftanh(gg);
      if (cprev) c += sigm(gf) * cprev[row * 768 + j];
      float h = sigm(go) * ftanh(c);
      if (hf) hf[row * 768 + j] = h;
      if (cf) cf[row * 768 + j] = c;
      if (hh) hh[row * 768 + j] = f2h(h);
      if (ch) ch[row * 768 + j] = f2h(c);
    }
  }
}

__device__ __forceinline__ void cvt_seg(const float* s, u16* d, int n4,
                                        int gtid, int nthr) {
  for (int i = gtid; i < n4; i += nthr) {
    float4 v = ((const float4*)s)[i];
    ushort4 h;
    h.x = f2h(v.x); h.y = f2h(v.y); h.z = f2h(v.z); h.w = f2h(v.w);
    ((ushort4*)d)[i] = h;
  }
}

// ---------------------------------------------------------------------------
__global__ __launch_bounds__(256)
void cvt0_k(const float* x, u16* xh, const float* Wih, u16* Wihh,
            const float* Whh3, u16* Whh3h, const float* hfcW, u16* hfcTh)
{
  const int g = blockIdx.x * 256 + threadIdx.x, N = 2048 * 256;
  cvt_seg(x,    xh,    196608,  g, N);
  cvt_seg(Wih,  Wihh,  1769472, g, N);
  cvt_seg(Whh3, Whh3h, 589824,  g, N);
  for (int i = g; i < 589824; i += N) {      // hfcT[k][m] = hfcW[m][k]
    const int k = i / 768, m = i - k * 768;
    hfcTh[i] = f2h(hfcW[m * 768 + k]);
  }
}

struct K1P {
  const u16 *xh, *Wihh, *Whh3h, *hfcTh;
  const float *bih, *bhh, *Whh, *hfcb;
  float *h1f, *c1f, *b3f, *Gpre;
  u16 *h1h, *W2h;
  const float *cfcW, *midW, *o1W, *o2W, *o3W;
  u16 *Whh1h, *cfch, *midh, *o1h, *o2h, *o3h;
};

__global__ __launch_bounds__(256)
void k1_k(K1P p)
{
  __shared__ __align__(16) u16 As[4 * 64 * 32];
  __shared__ __align__(16) u16 Bs[4 * 128 * 32];
  const int blk = blockIdx.x, tid = threadIdx.x;

  if (blk < 384) {
    run_cell(p.xh, p.Wihh, p.bih, p.bhh, nullptr, nullptr,
             p.h1f, p.c1f, p.h1h, nullptr, blk % 24, blk / 24, As, Bs, tid);
  } else if (blk < 1152) {
    const int r = blk - 384;
    GJob jb = { p.xh, p.Wihh + (size_t)3072 * 768, p.Gpre, nullptr,
                p.bih + 3072, p.bhh + 3072, nullptr, 6144, 6144, 0 };
    run_gemm(jb, r % 48, r / 48, As, Bs, tid);
  } else if (blk < 1440) {
    const int r = blk - 1152;
    GJob jb = { p.Whh3h, p.hfcTh, nullptr, p.W2h,
                nullptr, nullptr, nullptr, 768, 768, 0 };
    run_gemm(jb, r % 6, r / 6, As, Bs, tid);
  } else if (blk < 1452) {
    const int g = (blk - 1440) * 256 + tid;          // 0..3071
    const float* wrow = p.Whh + 4718592 + (size_t)g * 768;   // Whh task 2
    float s = 0.f;
    for (int m = 0; m < 768; m += 4) {
      float4 wv4 = *(const float4*)(wrow + m);
      float4 bv4 = *(const float4*)(p.hfcb + m);
      s += wv4.x * bv4.x + wv4.y * bv4.y + wv4.z * bv4.z + wv4.w * bv4.w;
    }
    p.b3f[g] = s;
  } else {
    const int g = (blk - 1452) * 256 + tid, N = 84 * 256;
    cvt_seg(p.Whh + 2359296, p.Whh1h, 589824, g, N);   // Whh task 1
    cvt_seg(p.cfcW, p.cfch, 147456, g, N);
    cvt_seg(p.midW, p.midh, 442368, g, N);
    cvt_seg(p.o1W,  p.o1h,  38784,  g, N);
    cvt_seg(p.o2W,  p.o2h,  35136,  g, N);
    cvt_seg(p.o3W,  p.o3h,  2112,   g, N);
  }
}

__global__ __launch_bounds__(256)
void cell2_k(const u16* __restrict__ A, const u16* __restrict__ W,
             const float* __restrict__ addend, const float* __restrict__ cprev,
             float* hf, u16* hh, u16* ch)
{
  __shared__ __align__(16) u16 As[4 * 64 * 32];
  __shared__ __align__(16) u16 Bs[4 * 128 * 32];
  run_cell(A, W, nullptr, nullptr, addend, cprev, hf, nullptr, hh, ch,
           blockIdx.x, blockIdx.y, As, Bs, threadIdx.x);
}

__global__ __launch_bounds__(256)
void cell3_k(const u16* __restrict__ h1h, const u16* __restrict__ h2h,
             const u16* __restrict__ c2h,
             const u16* __restrict__ Whh3h, const u16* __restrict__ W2h,
             const u16* __restrict__ cfch,
             const float* __restrict__ b3f, const float* __restrict__ Gpre3,
             const float* __restrict__ c1f, const float* __restrict__ cfcb,
             float* __restrict__ h3f)
{
  __shared__ __align__(16) u16 As[4 * 64 * 32];
  __shared__ __align__(16) u16 Bs[4 * 128 * 32];
  const int bj0 = blockIdx.x * 32;
  const int bm0 = blockIdx.y * 64;
  const int tid = threadIdx.x, lane = tid & 63, wv = tid >> 6;
  const int frow = lane & 15, fsl = lane >> 4;

  const int ra  = tid >> 2,        csa  = (tid & 3) ^ SWZ(ra);
  const int rb1 = (tid >> 2) + 64, csb1 = (tid & 3) ^ SWZ(rb1);
  const int wr0 = (ra >> 5) * 768 + bj0 + (ra & 31);
  const int wr1 = (rb1 >> 5) * 768 + bj0 + (rb1 & 31);

  KP kp;
  kp.pA1   = h1h + (size_t)(bm0 + ra) * 768 + csa * 8;
  kp.pA2   = h2h + (size_t)(bm0 + ra) * 768 + csa * 8;
  kp.pW1_0 = Whh3h + (size_t)wr0 * 768 + csa * 8;
  kp.pW2_0 = W2h   + (size_t)wr0 * 768 + csa * 8;
  kp.pW1_1 = Whh3h + (size_t)wr1 * 768 + csb1 * 8;
  kp.pW2_1 = W2h   + (size_t)wr1 * 768 + csb1 * 8;

  f32x4 acc[8];
#pragma unroll
  for (int n = 0; n < 8; ++n) acc[n] = (f32x4){0.f, 0.f, 0.f, 0.f};

  kloop4(kp, 24, 48, As, Bs, wv, frow, fsl, acc);

  // mini-pipeline: cfc_acc[64x32] = c2 * cfcW^T   (2 loads/thread/tile)
  const int qb = tid & 127;
  const int rc = qb >> 2, csc = (qb & 3) ^ SWZ(rc);
  const u16* pA3 = c2h  + (size_t)(bm0 + ra) * 768 + csa * 8;
  const u16* pC  = cfch + (size_t)(bj0 + rc) * 768 + csc * 8;
  const int bdst = (wv < 2) ? wv * 512 : 1024 + wv * 512;  // waves 2,3: dummy

  f32x4 accc[2];
  accc[0] = (f32x4){0.f, 0.f, 0.f, 0.f};
  accc[1] = (f32x4){0.f, 0.f, 0.f, 0.f};

#define MSTAGE(t) do { const int mb_ = (t) & 3;                         \
    gld16(pA3 + (t) * 32, As + mb_ * 2048 + wv * 512);                  \
    gld16(pC  + (t) * 32, Bs + mb_ * 4096 + bdst); } while (0)
#define MCOMP(t) do { const int mb_ = (t) & 3;                          \
    const u16* Ab_ = As + mb_ * 2048; const u16* Bb_ = Bs + mb_ * 4096; \
    const int ar_ = wv * 16 + frow;                                     \
    f16x8 ah_ = *(const f16x8*)(Ab_ + ar_ * 32 + ((fsl ^ SWZ(ar_)) * 8)); \
    const int b0_ = frow, b1_ = 16 + frow;                              \
    f16x8 f0_ = *(const f16x8*)(Bb_ + b0_ * 32 + ((fsl ^ SWZ(b0_)) * 8)); \
    f16x8 f1_ = *(const f16x8*)(Bb_ + b1_ * 32 + ((fsl ^ SWZ(b1_)) * 8)); \
    accc[0] = __builtin_amdgcn_mfma_f32_16x16x32_f16(ah_, f0_, accc[0], 0, 0, 0); \
    accc[1] = __builtin_amdgcn_mfma_f32_16x16x32_f16(ah_, f1_, accc[1], 0, 0, 0); \
  } while (0)

  MSTAGE(0); MSTAGE(1); MSTAGE(2);
  for (int t = 0; t < 22; ++t) {
    VMCNT(4); KBAR();
    MCOMP(t);
    if (t + 3 < 24) MSTAGE(t + 3);
  }
  VMCNT(2); KBAR();
  MCOMP(22);
  VMCNT(0); KBAR();
  MCOMP(23);
#undef MSTAGE
#undef MCOMP

  const int rb = (lane >> 4) * 4;
  const int cc = lane & 15;
#pragma unroll
  for (int jj = 0; jj < 2; ++jj) {
    const int j = bj0 + jj * 16 + cc;
    const float b_i = b3f[j];
    const float b_f = b3f[768 + j];
    const float b_g = b3f[1536 + j];
    const float b_o = b3f[2304 + j];
    const float cb_ = cfcb[j];
    const int row0 = bm0 + wv * 16 + rb;
#pragma unroll
    for (int r = 0; r < 4; ++r) {
      const int row = row0 + r;
      const float* ad = Gpre3 + (size_t)row * 6144;
      float gi = acc[0 + jj][r] + b_i + ad[j];
      float gf = acc[2 + jj][r] + b_f + ad[768 + j];
      float gg = acc[4 + jj][r] + b_g + ad[1536 + j];
      float go = acc[6 + jj][r] + b_o + ad[2304 + j];
      float cp3 = accc[jj][r] + c1f[row * 768 + j] + cb_;
      float c = sigm(gf) * cp3 + sigm(gi) * ftanh(gg);
      h3f[row * 768 + j] = sigm(go) * ftanh(c);
    }
  }
}

struct GArgs { GJob j[3]; };

__global__ __launch_bounds__(256)
void gemm_k(GArgs P)
{
  __shared__ __align__(16) u16 As[4 * 64 * 32];
  __shared__ __align__(16) u16 Bs[4 * 128 * 32];
  run_gemm(P.j[blockIdx.z], blockIdx.x, blockIdx.y, As, Bs, threadIdx.x);
}

__global__ __launch_bounds__(256)
void attn_k(const float* __restrict__ attn,
            const float* __restrict__ h1, const float* __restrict__ h2,
            const float* __restrict__ h3,
            u16* __restrict__ a1, u16* __restrict__ a2, u16* __restrict__ a3)
{
  const int b = blockIdx.x, tid = threadIdx.x;
  const int lane = tid & 63, wv = tid >> 6;
  __shared__ float accW[4][3][768];
  __shared__ float lsumW[4][3];

  const float* ab = attn + (size_t)b * 196608;
  const int cb = lane * 4;

  float4 hh[3][3];
#pragma unroll
  for (int j = 0; j < 3; ++j) {
    hh[0][j] = *(const float4*)(h1 + b * 768 + j * 256 + cb);
    hh[1][j] = *(const float4*)(h2 + b * 768 + j * 256 + cb);
    hh[2][j] = *(const float4*)(h3 + b * 768 + j * 256 + cb);
  }

  float4 acc[3][3];
#pragma unroll
  for (int t3 = 0; t3 < 3; ++t3)
#pragma unroll
    for (int j = 0; j < 3; ++j) acc[t3][j] = (float4){0.f, 0.f, 0.f, 0.f};
  float lsum[3] = {0.f, 0.f, 0.f};

  const int row0 = wv * 64;
  for (int sub = 0; sub < 16; ++sub) {
    const float* rp = ab + (size_t)(row0 + sub * 4) * 768 + cb;
    float4 vv[4][3];
#pragma unroll
    for (int s = 0; s < 4; ++s)
#pragma unroll
      for (int j = 0; j < 3; ++j)
        vv[s][j] = *(const float4*)(rp + s * 768 + j * 256);

    float q[3][4];
#pragma unroll
    for (int t3 = 0; t3 < 3; ++t3)
#pragma unroll
      for (int s = 0; s < 4; ++s) {
        float d = 0.f;
#pragma unroll
        for (int j = 0; j < 3; ++j) {
          d = fmaf(vv[s][j].x, hh[t3][j].x, d);
          d = fmaf(vv[s][j].y, hh[t3][j].y, d);
          d = fmaf(vv[s][j].z, hh[t3][j].z, d);
          d = fmaf(vv[s][j].w, hh[t3][j].w, d);
        }
        q[t3][s] = d;
      }
#pragma unroll
    for (int t3 = 0; t3 < 3; ++t3)
#pragma unroll
      for (int s = 0; s < 4; ++s) {
#pragma unroll
        for (int d = 1; d < 64; d <<= 1)
          q[t3][s] += __shfl_xor(q[t3][s], d);
        q[t3][s] = __expf(q[t3][s]);
      }
#pragma unroll
    for (int t3 = 0; t3 < 3; ++t3)
#pragma unroll
      for (int s = 0; s < 4; ++s) {
        const float pw = q[t3][s];
        lsum[t3] += pw;
#pragma unroll
        for (int j = 0; j < 3; ++j) {
          acc[t3][j].x = fmaf(pw, vv[s][j].x, acc[t3][j].x);
          acc[t3][j].y = fmaf(pw, vv[s][j].y, acc[t3][j].y);
          acc[t3][j].z = fmaf(pw, vv[s][j].z, acc[t3][j].z);
          acc[t3][j].w = fmaf(pw, vv[s][j].w, acc[t3][j].w);
        }
      }
  }

#pragma unroll
  for (int t3 = 0; t3 < 3; ++t3)
#pragma unroll
    for (int j = 0; j < 3; ++j)
      *(float4*)(&accW[wv][t3][j * 256 + cb]) = acc[t3][j];
  if (lane == 0) {
#pragma unroll
    for (int t3 = 0; t3 < 3; ++t3) lsumW[wv][t3] = lsum[t3];
  }
  __syncthreads();

  float ltot[3];
#pragma unroll
  for (int t3 = 0; t3 < 3; ++t3)
    ltot[t3] = lsumW[0][t3] + lsumW[1][t3] + lsumW[2][t3] + lsumW[3][t3];
  u16* outs[3] = { a1, a2, a3 };
#pragma unroll
  for (int cc = 0; cc < 3; ++cc) {
    const int c = tid + cc * 256;
#pragma unroll
    for (int t3 = 0; t3 < 3; ++t3) {
      float s = accW[0][t3][c] + accW[1][t3][c] + accW[2][t3][c] + accW[3][t3][c];
      outs[t3][b * 768 + c] = f2h(s / ltot[t3]);
    }
  }
}

// ---------------------------------------------------------------------------
extern "C" void kernel_launch(void* const* d_in, const int* in_sizes, int n_in,
                              void* d_out, int out_size, void* d_ws, size_t ws_size,
                              hipStream_t stream)
{
  const float* x    = (const float*)d_in[0];
  const float* attn = (const float*)d_in[1];
  const float* Wih  = (const float*)d_in[2];
  const float* Whh  = (const float*)d_in[3];
  const float* bih  = (const float*)d_in[4];
  const float* bhh  = (const float*)d_in[5];
  const float* hfcW = (const float*)d_in[6];
  const float* hfcb = (const float*)d_in[7];
  const float* cfcW = (const float*)d_in[8];
  const float* cfcb = (const float*)d_in[9];
  const float* midW = (const float*)d_in[10];
  const float* midb = (const float*)d_in[11];
  const float* o1W  = (const float*)d_in[12];
  const float* o1b  = (const float*)d_in[13];
  const float* o2W  = (const float*)d_in[14];
  const float* o2b  = (const float*)d_in[15];
  const float* o3W  = (const float*)d_in[16];
  const float* o3b  = (const float*)d_in[17];
  float* out = (float*)d_out;
  char*  ws  = (char*)d_ws;

  float* Gpre  = (float*)(ws + 0);
  float* h1f   = (float*)(ws + 25165824);
  float* c1f   = (float*)(ws + 28311552);
  float* h2f   = (float*)(ws + 31457280);
  float* h3f   = (float*)(ws + 34603008);
  float* b3f   = (float*)(ws + 37748736);
  u16*   xh    = (u16*)(ws + 37765120);
  u16*   Wihh  = (u16*)(ws + 39337984);
  u16*   Whh1h = (u16*)(ws + 53493760);
  u16*   Whh3h = (u16*)(ws + 58212352);
  u16*   hfcTh = (u16*)(ws + 62930944);
  u16*   W2h   = (u16*)(ws + 64110592);
  u16*   cfch  = (u16*)(ws + 68829184);
  u16*   midh  = (u16*)(ws + 70008832);
  u16*   o1h   = (u16*)(ws + 73547776);
  u16*   o2h   = (u16*)(ws + 73858048);
  u16*   o3h   = (u16*)(ws + 74139648);
  u16*   h1h   = (u16*)(ws + 74157056);
  u16*   h2h   = (u16*)(ws + 75729920);
  u16*   c2h   = (u16*)(ws + 77302784);
  u16*   a1h   = (u16*)(ws + 78875648);
  u16*   a2h   = (u16*)(ws + 80448512);
  u16*   a3h   = (u16*)(ws + 82021376);
  u16*   m1h   = (u16*)(ws + 83594240);
  u16*   m2h   = (u16*)(ws + 85167104);
  u16*   m3h   = (u16*)(ws + 86739968);
  // workspace end: 88,312,832 bytes

  cvt0_k<<<2048, 256, 0, stream>>>(x, xh, Wih, Wihh,
                                   Whh + 4718592, Whh3h, hfcW, hfcTh);

  K1P p1;
  p1.xh = xh; p1.Wihh = Wihh; p1.Whh3h = Whh3h; p1.hfcTh = hfcTh;
  p1.bih = bih; p1.bhh = bhh; p1.Whh = Whh; p1.hfcb = hfcb;
  p1.h1f = h1f; p1.c1f = c1f; p1.b3f = b3f; p1.Gpre = Gpre;
  p1.h1h = h1h; p1.W2h = W2h;
  p1.cfcW = cfcW; p1.midW = midW;
  p1.o1W = o1W; p1.o2W = o2W; p1.o3W = o3W;
  p1.Whh1h = Whh1h; p1.cfch = cfch; p1.midh = midh;
  p1.o1h = o1h; p1.o2h = o2h; p1.o3h = o3h;
  k1_k<<<1536, 256, 0, stream>>>(p1);

  cell2_k<<<dim3(24, 16), 256, 0, stream>>>(h1h, Whh1h, Gpre, c1f,
                                            h2f, h2h, c2h);

  cell3_k<<<dim3(24, 16), 256, 0, stream>>>(h1h, h2h, c2h, Whh3h, W2h, cfch,
                                            b3f, Gpre + 3072, c1f, cfcb, h3f);

  attn_k<<<1024, 256, 0, stream>>>(attn, h1f, h2f, h3f, a1h, a2h, a3h);

  GArgs P;
  P = GArgs{};
  P.j[0] = { a1h, midh,           nullptr, m1h, midb,        nullptr, nullptr, 768, 768, 1 };
  P.j[1] = { a2h, midh +  589824, nullptr, m2h, midb +  768, nullptr, nullptr, 768, 768, 1 };
  P.j[2] = { a3h, midh + 1179648, nullptr, m3h, midb + 1536, nullptr, nullptr, 768, 768, 1 };
  gemm_k<<<dim3(6, 16, 3), 256, 0, stream>>>(P);

  P = GArgs{};
  P.j[0] = { m1h, o1h, out,          nullptr, o1b, nullptr, nullptr, 202, 202, 0 };
  P.j[1] = { m2h, o2h, out + 206848, nullptr, o2b, nullptr, nullptr, 183, 183, 0 };
  P.j[2] = { m3h, o3h, out + 394240, nullptr, o3b, nullptr, nullptr,  11,  11, 0 };
  gemm_k<<<dim3(2, 16, 3), 256, 0, stream>>>(P);

  (void)in_sizes; (void)n_in; (void)out_size; (void)ws_size;
}

// Round 10
// 349.637 us; speedup vs baseline: 1.0019x; 1.0019x over previous
//
#include <hip/hip_runtime.h>

// ---------------------------------------------------------------------------
// LSTMDecoder: 3 chained LSTM cells + edge FC + 3-head attention + heads.
// B=1024, H=768, S=256, C=(202,183,11).
// R9: K3 (hfc/cfc) eliminated: gates3 = Gpre3 + h1*Whh3^T + h2*W2'^T + b3'
// with W2' = Whh3*hfcW and b3' = Whh3*hfcb precomputed in K1's idle blocks;
// cp3 computed inside cell3 by a sequential mini-pipeline. 7 nodes.
// fp16 MFMA, 4-buffer counted-vmcnt (6/3/0 main, 4/2/0 mini), fused cell
// epilogues, fused coalesced single-pass fp32 attention.
// Whh layout [3,3072,768]: task t base = Whh + t*2359296.
// ---------------------------------------------------------------------------

typedef unsigned short u16;
typedef _Float16       f16x8 __attribute__((ext_vector_type(8)));
typedef float          f32x4 __attribute__((ext_vector_type(4)));

#define SWZ(r) ((((r) + ((r) >> 2))) & 3)
#define VMCNT(N) asm volatile("s_waitcnt vmcnt(" #N ")" ::: "memory")
#define KBAR()  do { __builtin_amdgcn_s_barrier(); __builtin_amdgcn_sched_barrier(0); } while (0)

__device__ __forceinline__ u16 f2h(float f) {
  _Float16 h = (_Float16)f;
  return __builtin_bit_cast(u16, h);
}
__device__ __forceinline__ float sigm(float x) { return 1.f / (1.f + __expf(-x)); }
__device__ __forceinline__ float ftanh(float x) { return 1.f - 2.f / (__expf(2.f * x) + 1.f); }

__device__ __forceinline__ void gld16(const u16* g, u16* l) {
  __builtin_amdgcn_global_load_lds(
      (const __attribute__((address_space(1))) unsigned int*)(g),
      (__attribute__((address_space(3))) unsigned int*)(l),
      16, 0, 0);
}

struct KP { const u16 *pA1, *pA2, *pW1_0, *pW2_0, *pW1_1, *pW2_1; };

__device__ __forceinline__ void stage_tile(const KP& kp, int kt, int ntA,
                                           u16* Asb, u16* Bsb, int wv) {
  const bool s1 = (kt < ntA);
  const int off = (s1 ? kt : kt - ntA) * 32;
  gld16((s1 ? kp.pA1   : kp.pA2  ) + off, Asb + wv * 512);
  gld16((s1 ? kp.pW1_0 : kp.pW2_0) + off, Bsb + wv * 512);
  gld16((s1 ? kp.pW1_1 : kp.pW2_1) + off, Bsb + 2048 + wv * 512);
}

__device__ __forceinline__ void compute_tile(const u16* Asb, const u16* Bsb,
                                             int wv, int frow, int fsl, f32x4* acc) {
  const int ar = wv * 16 + frow;
  f16x8 ah = *(const f16x8*)(Asb + ar * 32 + ((fsl ^ SWZ(ar)) * 8));
  f16x8 bh[8];
#pragma unroll
  for (int n = 0; n < 8; ++n) {
    const int br = n * 16 + frow;
    bh[n] = *(const f16x8*)(Bsb + br * 32 + ((fsl ^ SWZ(br)) * 8));
  }
#pragma unroll
  for (int n = 0; n < 8; ++n)
    acc[n] = __builtin_amdgcn_mfma_f32_16x16x32_f16(ah, bh[n], acc[n], 0, 0, 0);
}

__device__ __forceinline__ void kloop4(const KP& kp, int ntA, int NT,
                                       u16* As, u16* Bs,
                                       int wv, int frow, int fsl, f32x4* acc) {
  stage_tile(kp, 0, ntA, As,        Bs,        wv);
  stage_tile(kp, 1, ntA, As + 2048, Bs + 4096, wv);
  stage_tile(kp, 2, ntA, As + 4096, Bs + 8192, wv);
  for (int t = 0; t < NT - 2; ++t) {
    VMCNT(6); KBAR();
    const int cb = t & 3;
    compute_tile(As + cb * 2048, Bs + cb * 4096, wv, frow, fsl, acc);
    if (t + 3 < NT) {
      const int sb = (t + 3) & 3;
      stage_tile(kp, t + 3, ntA, As + sb * 2048, Bs + sb * 4096, wv);
    }
  }
  VMCNT(3); KBAR();
  compute_tile(As + ((NT - 2) & 3) * 2048, Bs + ((NT - 2) & 3) * 4096,
               wv, frow, fsl, acc);
  VMCNT(0); KBAR();
  compute_tile(As + ((NT - 1) & 3) * 2048, Bs + ((NT - 1) & 3) * 4096,
               wv, frow, fsl, acc);
}

// ---------------------------------------------------------------------------
struct GJob {
  const u16* A; const u16* W;
  float* outf; u16* outh;
  const float* bias; const float* bias2; const float* addend;
  int N; int ldc; int relu;
};

__device__ __forceinline__ void run_gemm(const GJob& jb, int bx, int by,
                                         u16* As, u16* Bs, int tid) {
  const int bn0 = bx * 128;
  if (bn0 >= jb.N) return;
  const int bm0 = by * 64;
  const int lane = tid & 63, wv = tid >> 6;
  const int frow = lane & 15, fsl = lane >> 4;

  const int ra  = tid >> 2,        csa  = (tid & 3) ^ SWZ(ra);
  const int rb1 = (tid >> 2) + 64, csb1 = (tid & 3) ^ SWZ(rb1);
  int wr0 = bn0 + ra;  if (wr0 >= jb.N) wr0 = jb.N - 1;
  int wr1 = bn0 + rb1; if (wr1 >= jb.N) wr1 = jb.N - 1;

  KP kp;
  kp.pA1 = kp.pA2 = jb.A + (size_t)(bm0 + ra) * 768 + csa * 8;
  kp.pW1_0 = kp.pW2_0 = jb.W + (size_t)wr0 * 768 + csa * 8;
  kp.pW1_1 = kp.pW2_1 = jb.W + (size_t)wr1 * 768 + csb1 * 8;

  f32x4 acc[8];
#pragma unroll
  for (int n = 0; n < 8; ++n) acc[n] = (f32x4){0.f, 0.f, 0.f, 0.f};

  kloop4(kp, 24, 24, As, Bs, wv, frow, fsl, acc);

  const int rb = (lane >> 4) * 4;
  const int cc = lane & 15;
#pragma unroll
  for (int n = 0; n < 8; ++n) {
    const int col = bn0 + n * 16 + cc;
    if (col >= jb.N) continue;
    float bv = 0.f;
    if (jb.bias)  bv += jb.bias[col];
    if (jb.bias2) bv += jb.bias2[col];
    const int row0 = bm0 + wv * 16 + rb;
#pragma unroll
    for (int r = 0; r < 4; ++r) {
      const int row = row0 + r;
      float v = acc[n][r] + bv;
      if (jb.addend) v += jb.addend[(size_t)row * jb.ldc + col];
      if (jb.relu)   v = fmaxf(v, 0.f);
      if (jb.outf)   jb.outf[(size_t)row * jb.ldc + col] = v;
      if (jb.outh)   jb.outh[(size_t)row * jb.ldc + col] = f2h(v);
    }
  }
}

__device__ __forceinline__ void run_cell(const u16* A, const u16* W,
                                         const float* bi, const float* bh_,
                                         const float* addend,
                                         const float* cprev,
                                         float* hf, float* cf, u16* hh, u16* ch,
                                         int bx, int by,
                                         u16* As, u16* Bs, int tid) {
  const int bj0 = bx * 32;
  const int bm0 = by * 64;
  const int lane = tid & 63, wv = tid >> 6;
  const int frow = lane & 15, fsl = lane >> 4;

  const int ra  = tid >> 2,        csa  = (tid & 3) ^ SWZ(ra);
  const int rb1 = (tid >> 2) + 64, csb1 = (tid & 3) ^ SWZ(rb1);
  const int wr0 = (ra >> 5) * 768 + bj0 + (ra & 31);
  const int wr1 = (rb1 >> 5) * 768 + bj0 + (rb1 & 31);

  KP kp;
  kp.pA1 = kp.pA2 = A + (size_t)(bm0 + ra) * 768 + csa * 8;
  kp.pW1_0 = kp.pW2_0 = W + (size_t)wr0 * 768 + csa * 8;
  kp.pW1_1 = kp.pW2_1 = W + (size_t)wr1 * 768 + csb1 * 8;

  f32x4 acc[8];
#pragma unroll
  for (int n = 0; n < 8; ++n) acc[n] = (f32x4){0.f, 0.f, 0.f, 0.f};

  kloop4(kp, 24, 24, As, Bs, wv, frow, fsl, acc);

  const int rb = (lane >> 4) * 4;
  const int cc = lane & 15;
#pragma unroll
  for (int jj = 0; jj < 2; ++jj) {
    const int j = bj0 + jj * 16 + cc;
    float b_i = 0.f, b_f = 0.f, b_g = 0.f, b_o = 0.f;
    if (bi) {
      b_i = bi[j]        + bh_[j];
      b_f = bi[768 + j]  + bh_[768 + j];
      b_g = bi[1536 + j] + bh_[1536 + j];
      b_o = bi[2304 + j] + bh_[2304 + j];
    }
    const int row0 = bm0 + wv * 16 + rb;
#pragma unroll
    for (int r = 0; r < 4; ++r) {
      const int row = row0 + r;
      float gi = acc[0 + jj][r] + b_i;
      float gf = acc[2 + jj][r] + b_f;
      float gg = acc[4 + jj][r] + b_g;
      float go = acc[6 + jj][r] + b_o;
      if (addend) {
        const float* ad = addend + (size_t)row * 6144;
        gi += ad[j]; gf += ad[768 + j]; gg += ad[1536 + j]; go += ad[2304 + j];
      }
      float c = sigm(gi) * ftanh(gg);
      if (cprev) c += sigm(gf) * cprev[row * 768 + j];
      float h = sigm(go) * ftanh(c);
      if (hf) hf[row * 768 + j] = h;
      if (cf) cf[row * 768 + j] = c;
      if (hh) hh[row * 768 + j] = f2h(h);
      if (ch) ch[row * 768 + j] = f2h(c);
    }
  }
}

__device__ __forceinline__ void cvt_seg(const float* s, u16* d, int n4,
                                        int gtid, int nthr) {
  for (int i = gtid; i < n4; i += nthr) {
    float4 v = ((const float4*)s)[i];
    ushort4 h;
    h.x = f2h(v.x); h.y = f2h(v.y); h.z = f2h(v.z); h.w = f2h(v.w);
    ((ushort4*)d)[i] = h;
  }
}

// ---------------------------------------------------------------------------
__global__ __launch_bounds__(256)
void cvt0_k(const float* x, u16* xh, const float* Wih, u16* Wihh,
            const float* Whh3, u16* Whh3h, const float* hfcW, u16* hfcTh)
{
  const int g = blockIdx.x * 256 + threadIdx.x, N = 2048 * 256;
  cvt_seg(x,    xh,    196608,  g, N);
  cvt_seg(Wih,  Wihh,  1769472, g, N);
  cvt_seg(Whh3, Whh3h, 589824,  g, N);
  for (int i = g; i < 589824; i += N) {      // hfcT[k][m] = hfcW[m][k]
    const int k = i / 768, m = i - k * 768;
    hfcTh[i] = f2h(hfcW[m * 768 + k]);
  }
}

struct K1P {
  const u16 *xh, *Wihh, *Whh3h, *hfcTh;
  const float *bih, *bhh, *Whh, *hfcb;
  float *h1f, *c1f, *b3f, *Gpre;
  u16 *h1h, *W2h;
  const float *cfcW, *midW, *o1W, *o2W, *o3W;
  u16 *Whh1h, *cfch, *midh, *o1h, *o2h, *o3h;
};

__global__ __launch_bounds__(256)
void k1_k(K1P p)
{
  __shared__ __align__(16) u16 As[4 * 64 * 32];
  __shared__ __align__(16) u16 Bs[4 * 128 * 32];
  const int blk = blockIdx.x, tid = threadIdx.x;

  if (blk < 384) {
    run_cell(p.xh, p.Wihh, p.bih, p.bhh, nullptr, nullptr,
             p.h1f, p.c1f, p.h1h, nullptr, blk % 24, blk / 24, As, Bs, tid);
  } else if (blk < 1152) {
    const int r = blk - 384;
    GJob jb = { p.xh, p.Wihh + (size_t)3072 * 768, p.Gpre, nullptr,
                p.bih + 3072, p.bhh + 3072, nullptr, 6144, 6144, 0 };
    run_gemm(jb, r % 48, r / 48, As, Bs, tid);
  } else if (blk < 1440) {
    const int r = blk - 1152;
    GJob jb = { p.Whh3h, p.hfcTh, nullptr, p.W2h,
                nullptr, nullptr, nullptr, 768, 768, 0 };
    run_gemm(jb, r % 6, r / 6, As, Bs, tid);
  } else if (blk < 1452) {
    const int g = (blk - 1440) * 256 + tid;          // 0..3071
    const float* wrow = p.Whh + 4718592 + (size_t)g * 768;   // Whh task 2
    float s = 0.f;
    for (int m = 0; m < 768; m += 4) {
      float4 wv4 = *(const float4*)(wrow + m);
      float4 bv4 = *(const float4*)(p.hfcb + m);
      s += wv4.x * bv4.x + wv4.y * bv4.y + wv4.z * bv4.z + wv4.w * bv4.w;
    }
    p.b3f[g] = s;
  } else {
    const int g = (blk - 1452) * 256 + tid, N = 84 * 256;
    cvt_seg(p.Whh + 2359296, p.Whh1h, 589824, g, N);   // Whh task 1
    cvt_seg(p.cfcW, p.cfch, 147456, g, N);
    cvt_seg(p.midW, p.midh, 442368, g, N);
    cvt_seg(p.o1W,  p.o1h,  38784,  g, N);
    cvt_seg(p.o2W,  p.o2h,  35136,  g, N);
    cvt_seg(p.o3W,  p.o3h,  2112,   g, N);
  }
}

__global__ __launch_bounds__(256)
void cell2_k(const u16* __restrict__ A, const u16* __restrict__ W,
             const float* __restrict__ addend, const float* __restrict__ cprev,
             float* hf, u16* hh, u16* ch)
{
  __shared__ __align__(16) u16 As[4 * 64 * 32];
  __shared__ __align__(16) u16 Bs[4 * 128 * 32];
  run_cell(A, W, nullptr, nullptr, addend, cprev, hf, nullptr, hh, ch,
           blockIdx.x, blockIdx.y, As, Bs, threadIdx.x);
}

__global__ __launch_bounds__(256)
void cell3_k(const u16* __restrict__ h1h, const u16* __restrict__ h2h,
             const u16* __restrict__ c2h,
             const u16* __restrict__ Whh3h, const u16* __restrict__ W2h,
             const u16* __restrict__ cfch,
             const float* __restrict__ b3f, const float* __restrict__ Gpre3,
             const float* __restrict__ c1f, const float* __restrict__ cfcb,
             float* __restrict__ h3f)
{
  __shared__ __align__(16) u16 As[4 * 64 * 32];
  __shared__ __align__(16) u16 Bs[4 * 128 * 32];
  const int bj0 = blockIdx.x * 32;
  const int bm0 = blockIdx.y * 64;
  const int tid = threadIdx.x, lane = tid & 63, wv = tid >> 6;
  const int frow = lane & 15, fsl = lane >> 4;

  const int ra  = tid >> 2,        csa  = (tid & 3) ^ SWZ(ra);
  const int rb1 = (tid >> 2) + 64, csb1 = (tid & 3) ^ SWZ(rb1);
  const int wr0 = (ra >> 5) * 768 + bj0 + (ra & 31);
  const int wr1 = (rb1 >> 5) * 768 + bj0 + (rb1 & 31);

  KP kp;
  kp.pA1   = h1h + (size_t)(bm0 + ra) * 768 + csa * 8;
  kp.pA2   = h2h + (size_t)(bm0 + ra) * 768 + csa * 8;
  kp.pW1_0 = Whh3h + (size_t)wr0 * 768 + csa * 8;
  kp.pW2_0 = W2h   + (size_t)wr0 * 768 + csa * 8;
  kp.pW1_1 = Whh3h + (size_t)wr1 * 768 + csb1 * 8;
  kp.pW2_1 = W2h   + (size_t)wr1 * 768 + csb1 * 8;

  f32x4 acc[8];
#pragma unroll
  for (int n = 0; n < 8; ++n) acc[n] = (f32x4){0.f, 0.f, 0.f, 0.f};

  kloop4(kp, 24, 48, As, Bs, wv, frow, fsl, acc);

  // mini-pipeline: cfc_acc[64x32] = c2 * cfcW^T   (2 loads/thread/tile)
  const int qb = tid & 127;
  const int rc = qb >> 2, csc = (qb & 3) ^ SWZ(rc);
  const u16* pA3 = c2h  + (size_t)(bm0 + ra) * 768 + csa * 8;
  const u16* pC  = cfch + (size_t)(bj0 + rc) * 768 + csc * 8;
  const int bdst = (wv < 2) ? wv * 512 : 1024 + wv * 512;  // waves 2,3: dummy

  f32x4 accc[2];
  accc[0] = (f32x4){0.f, 0.f, 0.f, 0.f};
  accc[1] = (f32x4){0.f, 0.f, 0.f, 0.f};

#define MSTAGE(t) do { const int mb_ = (t) & 3;                         \
    gld16(pA3 + (t) * 32, As + mb_ * 2048 + wv * 512);                  \
    gld16(pC  + (t) * 32, Bs + mb_ * 4096 + bdst); } while (0)
#define MCOMP(t) do { const int mb_ = (t) & 3;                          \
    const u16* Ab_ = As + mb_ * 2048; const u16* Bb_ = Bs + mb_ * 4096; \
    const int ar_ = wv * 16 + frow;                                     \
    f16x8 ah_ = *(const f16x8*)(Ab_ + ar_ * 32 + ((fsl ^ SWZ(ar_)) * 8)); \
    const int b0_ = frow, b1_ = 16 + frow;                              \
    f16x8 f0_ = *(const f16x8*)(Bb_ + b0_ * 32 + ((fsl ^ SWZ(b0_)) * 8)); \
    f16x8 f1_ = *(const f16x8*)(Bb_ + b1_ * 32 + ((fsl ^ SWZ(b1_)) * 8)); \
    accc[0] = __builtin_amdgcn_mfma_f32_16x16x32_f16(ah_, f0_, accc[0], 0, 0, 0); \
    accc[1] = __builtin_amdgcn_mfma_f32_16x16x32_f16(ah_, f1_, accc[1], 0, 0, 0); \
  } while (0)

  MSTAGE(0); MSTAGE(1); MSTAGE(2);
  for (int t = 0; t < 22; ++t) {
    VMCNT(4); KBAR();
    MCOMP(t);
    if (t + 3 < 24) MSTAGE(t + 3);
  }
  VMCNT(2); KBAR();
  MCOMP(22);
  VMCNT(0); KBAR();
  MCOMP(23);
#undef MSTAGE
#undef MCOMP

  const int rb = (lane >> 4) * 4;
  const int cc = lane & 15;
#pragma unroll
  for (int jj = 0; jj < 2; ++jj) {
    const int j = bj0 + jj * 16 + cc;
    const float b_i = b3f[j];
    const float b_f = b3f[768 + j];
    const float b_g = b3f[1536 + j];
    const float b_o = b3f[2304 + j];
    const float cb_ = cfcb[j];
    const int row0 = bm0 + wv * 16 + rb;
#pragma unroll
    for (int r = 0; r < 4; ++r) {
      const int row = row0 + r;
      const float* ad = Gpre3 + (size_t)row * 6144;
      float gi = acc[0 + jj][r] + b_i + ad[j];
      float gf = acc[2 + jj][r] + b_f + ad[768 + j];
      float gg = acc[4 + jj][r] + b_g + ad[1536 + j];
      float go = acc[6 + jj][r] + b_o + ad[2304 + j];
      float cp3 = accc[jj][r] + c1f[row * 768 + j] + cb_;
      float c = sigm(gf) * cp3 + sigm(gi) * ftanh(gg);
      h3f[row * 768 + j] = sigm(go) * ftanh(c);
    }
  }
}

struct GArgs { GJob j[3]; };

__global__ __launch_bounds__(256)
void gemm_k(GArgs P)
{
  __shared__ __align__(16) u16 As[4 * 64 * 32];
  __shared__ __align__(16) u16 Bs[4 * 128 * 32];
  run_gemm(P.j[blockIdx.z], blockIdx.x, blockIdx.y, As, Bs, threadIdx.x);
}

__global__ __launch_bounds__(256)
void attn_k(const float* __restrict__ attn,
            const float* __restrict__ h1, const float* __restrict__ h2,
            const float* __restrict__ h3,
            u16* __restrict__ a1, u16* __restrict__ a2, u16* __restrict__ a3)
{
  const int b = blockIdx.x, tid = threadIdx.x;
  const int lane = tid & 63, wv = tid >> 6;
  __shared__ float accW[4][3][768];
  __shared__ float lsumW[4][3];

  const float* ab = attn + (size_t)b * 196608;
  const int cb = lane * 4;

  float4 hh[3][3];
#pragma unroll
  for (int j = 0; j < 3; ++j) {
    hh[0][j] = *(const float4*)(h1 + b * 768 + j * 256 + cb);
    hh[1][j] = *(const float4*)(h2 + b * 768 + j * 256 + cb);
    hh[2][j] = *(const float4*)(h3 + b * 768 + j * 256 + cb);
  }

  float4 acc[3][3];
#pragma unroll
  for (int t3 = 0; t3 < 3; ++t3)
#pragma unroll
    for (int j = 0; j < 3; ++j) acc[t3][j] = (float4){0.f, 0.f, 0.f, 0.f};
  float lsum[3] = {0.f, 0.f, 0.f};

  const int row0 = wv * 64;
  for (int sub = 0; sub < 16; ++sub) {
    const float* rp = ab + (size_t)(row0 + sub * 4) * 768 + cb;
    float4 vv[4][3];
#pragma unroll
    for (int s = 0; s < 4; ++s)
#pragma unroll
      for (int j = 0; j < 3; ++j)
        vv[s][j] = *(const float4*)(rp + s * 768 + j * 256);

    float q[3][4];
#pragma unroll
    for (int t3 = 0; t3 < 3; ++t3)
#pragma unroll
      for (int s = 0; s < 4; ++s) {
        float d = 0.f;
#pragma unroll
        for (int j = 0; j < 3; ++j) {
          d = fmaf(vv[s][j].x, hh[t3][j].x, d);
          d = fmaf(vv[s][j].y, hh[t3][j].y, d);
          d = fmaf(vv[s][j].z, hh[t3][j].z, d);
          d = fmaf(vv[s][j].w, hh[t3][j].w, d);
        }
        q[t3][s] = d;
      }
#pragma unroll
    for (int t3 = 0; t3 < 3; ++t3)
#pragma unroll
      for (int s = 0; s < 4; ++s) {
#pragma unroll
        for (int d = 1; d < 64; d <<= 1)
          q[t3][s] += __shfl_xor(q[t3][s], d);
        q[t3][s] = __expf(q[t3][s]);
      }
#pragma unroll
    for (int t3 = 0; t3 < 3; ++t3)
#pragma unroll
      for (int s = 0; s < 4; ++s) {
        const float pw = q[t3][s];
        lsum[t3] += pw;
#pragma unroll
        for (int j = 0; j < 3; ++j) {
          acc[t3][j].x = fmaf(pw, vv[s][j].x, acc[t3][j].x);
          acc[t3][j].y = fmaf(pw, vv[s][j].y, acc[t3][j].y);
          acc[t3][j].z = fmaf(pw, vv[s][j].z, acc[t3][j].z);
          acc[t3][j].w = fmaf(pw, vv[s][j].w, acc[t3][j].w);
        }
      }
  }

#pragma unroll
  for (int t3 = 0; t3 < 3; ++t3)
#pragma unroll
    for (int j = 0; j < 3; ++j)
      *(float4*)(&accW[wv][t3][j * 256 + cb]) = acc[t3][j];
  if (lane == 0) {
#pragma unroll
    for (int t3 = 0; t3 < 3; ++t3) lsumW[wv][t3] = lsum[t3];
  }
  __syncthreads();

  float ltot[3];
#pragma unroll
  for (int t3 = 0; t3 < 3; ++t3)
    ltot[t3] = lsumW[0][t3] + lsumW[1][t3] + lsumW[2][t3] + lsumW[3][t3];
  u16* outs[3] = { a1, a2, a3 };
#pragma unroll
  for (int cc = 0; cc < 3; ++cc) {
    const int c = tid + cc * 256;
#pragma unroll
    for (int t3 = 0; t3 < 3; ++t3) {
      float s = accW[0][t3][c] + accW[1][t3][c] + accW[2][t3][c] + accW[3][t3][c];
      outs[t3][b * 768 + c] = f2h(s / ltot[t3]);
    }
  }
}

// ---------------------------------------------------------------------------
extern "C" void kernel_launch(void* const* d_in, const int* in_sizes, int n_in,
                              void* d_out, int out_size, void* d_ws, size_t ws_size,
                              hipStream_t stream)
{
  const float* x    = (const float*)d_in[0];
  const float* attn = (const float*)d_in[1];
  const float* Wih  = (const float*)d_in[2];
  const float* Whh  = (const float*)d_in[3];
  const float* bih  = (const float*)d_in[4];
  const float* bhh  = (const float*)d_in[5];
  const float* hfcW = (const float*)d_in[6];
  const float* hfcb = (const float*)d_in[7];
  const float* cfcW = (const float*)d_in[8];
  const float* cfcb = (const float*)d_in[9];
  const float* midW = (const float*)d_in[10];
  const float* midb = (const float*)d_in[11];
  const float* o1W  = (const float*)d_in[12];
  const float* o1b  = (const float*)d_in[13];
  const float* o2W  = (const float*)d_in[14];
  const float* o2b  = (const float*)d_in[15];
  const float* o3W  = (const float*)d_in[16];
  const float* o3b  = (const float*)d_in[17];
  float* out = (float*)d_out;
  char*  ws  = (char*)d_ws;

  float* Gpre  = (float*)(ws + 0);
  float* h1f   = (float*)(ws + 25165824);
  float* c1f   = (float*)(ws + 28311552);
  float* h2f   = (float*)(ws + 31457280);
  float* h3f   = (float*)(ws + 34603008);
  float* b3f   = (float*)(ws + 37748736);
  u16*   xh    = (u16*)(ws + 37765120);
  u16*   Wihh  = (u16*)(ws + 39337984);
  u16*   Whh1h = (u16*)(ws + 53493760);
  u16*   Whh3h = (u16*)(ws + 58212352);
  u16*   hfcTh = (u16*)(ws + 62930944);
  u16*   W2h   = (u16*)(ws + 64110592);
  u16*   cfch  = (u16*)(ws + 68829184);
  u16*   midh  = (u16*)(ws + 70008832);
  u16*   o1h   = (u16*)(ws + 73547776);
  u16*   o2h   = (u16*)(ws + 73858048);
  u16*   o3h   = (u16*)(ws + 74139648);
  u16*   h1h   = (u16*)(ws + 74157056);
  u16*   h2h   = (u16*)(ws + 75729920);
  u16*   c2h   = (u16*)(ws + 77302784);
  u16*   a1h   = (u16*)(ws + 78875648);
  u16*   a2h   = (u16*)(ws + 80448512);
  u16*   a3h   = (u16*)(ws + 82021376);
  u16*   m1h   = (u16*)(ws + 83594240);
  u16*   m2h   = (u16*)(ws + 85167104);
  u16*   m3h   = (u16*)(ws + 86739968);
  // workspace end: 88,312,832 bytes

  cvt0_k<<<2048, 256, 0, stream>>>(x, xh, Wih, Wihh,
                                   Whh + 4718592, Whh3h, hfcW, hfcTh);

  K1P p1;
  p1.xh = xh; p1.Wihh = Wihh; p1.Whh3h = Whh3h; p1.hfcTh = hfcTh;
  p1.bih = bih; p1.bhh = bhh; p1.Whh = Whh; p1.hfcb = hfcb;
  p1.h1f = h1f; p1.c1f = c1f; p1.b3f = b3f; p1.Gpre = Gpre;
  p1.h1h = h1h; p1.W2h = W2h;
  p1.cfcW = cfcW; p1.midW = midW;
  p1.o1W = o1W; p1.o2W = o2W; p1.o3W = o3W;
  p1.Whh1h = Whh1h; p1.cfch = cfch; p1.midh = midh;
  p1.o1h = o1h; p1.o2h = o2h; p1.o3h = o3h;
  k1_k<<<1536, 256, 0, stream>>>(p1);

  cell2_k<<<dim3(24, 16), 256, 0, stream>>>(h1h, Whh1h, Gpre, c1f,
                                            h2f, h2h, c2h);

  cell3_k<<<dim3(24, 16), 256, 0, stream>>>(h1h, h2h, c2h, Whh3h, W2h, cfch,
                                            b3f, Gpre + 3072, c1f, cfcb, h3f);

  attn_k<<<1024, 256, 0, stream>>>(attn, h1f, h2f, h3f, a1h, a2h, a3h);

  GArgs P;
  P = GArgs{};
  P.j[0] = { a1h, midh,           nullptr, m1h, midb,        nullptr, nullptr, 768, 768, 1 };
  P.j[1] = { a2h, midh +  589824, nullptr, m2h, midb +  768, nullptr, nullptr, 768, 768, 1 };
  P.j[2] = { a3h, midh + 1179648, nullptr, m3h, midb + 1536, nullptr, nullptr, 768, 768, 1 };
  gemm_k<<<dim3(6, 16, 3), 256, 0, stream>>>(P);

  P = GArgs{};
  P.j[0] = { m1h, o1h, out,          nullptr, o1b, nullptr, nullptr, 202, 202, 0 };
  P.j[1] = { m2h, o2h, out + 206848, nullptr, o2b, nullptr, nullptr, 183, 183, 0 };
  P.j[2] = { m3h, o3h, out + 394240, nullptr, o3b, nullptr, nullptr,  11,  11, 0 };
  gemm_k<<<dim3(2, 16, 3), 256, 0, stream>>>(P);

  (void)in_sizes; (void)n_in; (void)out_size; (void)ws_size;
}

// Round 11
// 309.037 us; speedup vs baseline: 1.1335x; 1.1314x over previous
//
#include <hip/hip_runtime.h>

// ---------------------------------------------------------------------------
// LSTMDecoder: 3 chained LSTM cells + edge FC + 3-head attention + heads.
// B=1024, H=768, S=256, C=(202,183,11).
// R11 = R8 (best, 318.6us) + N-split 64-col tiles for all small-grid MFMA
// nodes (2x blocks -> 3-5/CU TLP on latency-bound nodes; 32KB LDS) +
// K1/K2 load rebalance (Gpre-task3 runs beside cell2 in K2).
// fp16 MFMA, counted-vmcnt pipelines (6/3/0 for 128-tiles, 4/2/0 for
// 64-tiles), fused LSTM-cell epilogues, fused coalesced single-pass fp32
// attention (R8-verbatim). 8 nodes.
// ---------------------------------------------------------------------------

typedef unsigned short u16;
typedef _Float16       f16x8 __attribute__((ext_vector_type(8)));
typedef float          f32x4 __attribute__((ext_vector_type(4)));

#define SWZ(r) ((((r) + ((r) >> 2))) & 3)
#define VMCNT(N) asm volatile("s_waitcnt vmcnt(" #N ")" ::: "memory")
#define KBAR()  do { __builtin_amdgcn_s_barrier(); __builtin_amdgcn_sched_barrier(0); } while (0)

__device__ __forceinline__ u16 f2h(float f) {
  _Float16 h = (_Float16)f;
  return __builtin_bit_cast(u16, h);
}
__device__ __forceinline__ float sigm(float x) { return 1.f / (1.f + __expf(-x)); }
__device__ __forceinline__ float ftanh(float x) { return 1.f - 2.f / (__expf(2.f * x) + 1.f); }

__device__ __forceinline__ void gld16(const u16* g, u16* l) {
  __builtin_amdgcn_global_load_lds(
      (const __attribute__((address_space(1))) unsigned int*)(g),
      (__attribute__((address_space(3))) unsigned int*)(l),
      16, 0, 0);
}

// ======================= 128-col-N path (R8-verbatim) ======================
struct KP { const u16 *pA, *pW0, *pW1; };

__device__ __forceinline__ void stage_tile(const KP& kp, int kt,
                                           u16* Asb, u16* Bsb, int wv) {
  const int off = kt * 32;
  gld16(kp.pA  + off, Asb + wv * 512);
  gld16(kp.pW0 + off, Bsb + wv * 512);
  gld16(kp.pW1 + off, Bsb + 2048 + wv * 512);
}

__device__ __forceinline__ void compute_tile(const u16* Asb, const u16* Bsb,
                                             int wv, int frow, int fsl, f32x4* acc) {
  const int ar = wv * 16 + frow;
  f16x8 ah = *(const f16x8*)(Asb + ar * 32 + ((fsl ^ SWZ(ar)) * 8));
  f16x8 bh[8];
#pragma unroll
  for (int n = 0; n < 8; ++n) {
    const int br = n * 16 + frow;
    bh[n] = *(const f16x8*)(Bsb + br * 32 + ((fsl ^ SWZ(br)) * 8));
  }
#pragma unroll
  for (int n = 0; n < 8; ++n)
    acc[n] = __builtin_amdgcn_mfma_f32_16x16x32_f16(ah, bh[n], acc[n], 0, 0, 0);
}

__device__ __forceinline__ void kloop4(const KP& kp, int NT, u16* As, u16* Bs,
                                       int wv, int frow, int fsl, f32x4* acc) {
  stage_tile(kp, 0, As,        Bs,        wv);
  stage_tile(kp, 1, As + 2048, Bs + 4096, wv);
  stage_tile(kp, 2, As + 4096, Bs + 8192, wv);
  for (int t = 0; t < NT - 2; ++t) {
    VMCNT(6); KBAR();
    const int cb = t & 3;
    compute_tile(As + cb * 2048, Bs + cb * 4096, wv, frow, fsl, acc);
    if (t + 3 < NT) {
      const int sb = (t + 3) & 3;
      stage_tile(kp, t + 3, As + sb * 2048, Bs + sb * 4096, wv);
    }
  }
  VMCNT(3); KBAR();
  compute_tile(As + ((NT - 2) & 3) * 2048, Bs + ((NT - 2) & 3) * 4096,
               wv, frow, fsl, acc);
  VMCNT(0); KBAR();
  compute_tile(As + ((NT - 1) & 3) * 2048, Bs + ((NT - 1) & 3) * 4096,
               wv, frow, fsl, acc);
}

struct GJob {
  const u16* A; const u16* W;
  float* outf; u16* outh;
  const float* bias; const float* bias2; const float* addend;
  int N; int ldc; int relu;
};

// 64 rows x 128 cols tile (Gpre only; needs As>=8192, Bs>=16384 u16)
__device__ __forceinline__ void run_gemm128(const GJob& jb, int bx, int by,
                                            u16* As, u16* Bs, int tid) {
  const int bn0 = bx * 128;
  if (bn0 >= jb.N) return;
  const int bm0 = by * 64;
  const int lane = tid & 63, wv = tid >> 6;
  const int frow = lane & 15, fsl = lane >> 4;

  const int ra  = tid >> 2,        csa  = (tid & 3) ^ SWZ(ra);
  const int rb1 = (tid >> 2) + 64, csb1 = (tid & 3) ^ SWZ(rb1);
  int wr0 = bn0 + ra;  if (wr0 >= jb.N) wr0 = jb.N - 1;
  int wr1 = bn0 + rb1; if (wr1 >= jb.N) wr1 = jb.N - 1;

  KP kp;
  kp.pA  = jb.A + (size_t)(bm0 + ra) * 768 + csa * 8;
  kp.pW0 = jb.W + (size_t)wr0 * 768 + csa * 8;
  kp.pW1 = jb.W + (size_t)wr1 * 768 + csb1 * 8;

  f32x4 acc[8];
#pragma unroll
  for (int n = 0; n < 8; ++n) acc[n] = (f32x4){0.f, 0.f, 0.f, 0.f};

  kloop4(kp, 24, As, Bs, wv, frow, fsl, acc);

  const int rb = (lane >> 4) * 4;
  const int cc = lane & 15;
#pragma unroll
  for (int n = 0; n < 8; ++n) {
    const int col = bn0 + n * 16 + cc;
    if (col >= jb.N) continue;
    float bv = 0.f;
    if (jb.bias)  bv += jb.bias[col];
    if (jb.bias2) bv += jb.bias2[col];
    const int row0 = bm0 + wv * 16 + rb;
#pragma unroll
    for (int r = 0; r < 4; ++r) {
      const int row = row0 + r;
      float v = acc[n][r] + bv;
      if (jb.addend) v += jb.addend[(size_t)row * jb.ldc + col];
      if (jb.relu)   v = fmaxf(v, 0.f);
      if (jb.outf)   jb.outf[(size_t)row * jb.ldc + col] = v;
      if (jb.outh)   jb.outh[(size_t)row * jb.ldc + col] = f2h(v);
    }
  }
}

// ======================= 64-col-N path (new, 2x grid) ======================
struct KP64 { const u16 *pA, *pW; };

__device__ __forceinline__ void stage64(const KP64& kp, int kt,
                                        u16* Asb, u16* Bsb, int wv) {
  const int off = kt * 32;
  gld16(kp.pA + off, Asb + wv * 512);
  gld16(kp.pW + off, Bsb + wv * 512);
}

__device__ __forceinline__ void compute64(const u16* Asb, const u16* Bsb,
                                          int wv, int frow, int fsl, f32x4* acc) {
  const int ar = wv * 16 + frow;
  f16x8 ah = *(const f16x8*)(Asb + ar * 32 + ((fsl ^ SWZ(ar)) * 8));
  f16x8 bh[4];
#pragma unroll
  for (int n = 0; n < 4; ++n) {
    const int br = n * 16 + frow;
    bh[n] = *(const f16x8*)(Bsb + br * 32 + ((fsl ^ SWZ(br)) * 8));
  }
#pragma unroll
  for (int n = 0; n < 4; ++n)
    acc[n] = __builtin_amdgcn_mfma_f32_16x16x32_f16(ah, bh[n], acc[n], 0, 0, 0);
}

// 2 loads/thread/tile -> counted vmcnt 4/2/0; 4 buffers of 2048 u16 each side
__device__ __forceinline__ void kloop64(const KP64& kp, int NT, u16* As, u16* Bs,
                                        int wv, int frow, int fsl, f32x4* acc) {
  stage64(kp, 0, As,        Bs,        wv);
  stage64(kp, 1, As + 2048, Bs + 2048, wv);
  stage64(kp, 2, As + 4096, Bs + 4096, wv);
  for (int t = 0; t < NT - 2; ++t) {
    VMCNT(4); KBAR();
    const int cb = t & 3;
    compute64(As + cb * 2048, Bs + cb * 2048, wv, frow, fsl, acc);
    if (t + 3 < NT) {
      const int sb = (t + 3) & 3;
      stage64(kp, t + 3, As + sb * 2048, Bs + sb * 2048, wv);
    }
  }
  VMCNT(2); KBAR();
  compute64(As + ((NT - 2) & 3) * 2048, Bs + ((NT - 2) & 3) * 2048,
            wv, frow, fsl, acc);
  VMCNT(0); KBAR();
  compute64(As + ((NT - 1) & 3) * 2048, Bs + ((NT - 1) & 3) * 2048,
            wv, frow, fsl, acc);
}

// plain GEMM, 64x64 tile
__device__ __forceinline__ void run_gemm64(const GJob& jb, int bx, int by,
                                           u16* As, u16* Bs, int tid) {
  const int bn0 = bx * 64;
  if (bn0 >= jb.N) return;
  const int bm0 = by * 64;
  const int lane = tid & 63, wv = tid >> 6;
  const int frow = lane & 15, fsl = lane >> 4;

  const int ra = tid >> 2, csa = (tid & 3) ^ SWZ(ra);
  int wr = bn0 + ra; if (wr >= jb.N) wr = jb.N - 1;

  KP64 kp;
  kp.pA = jb.A + (size_t)(bm0 + ra) * 768 + csa * 8;
  kp.pW = jb.W + (size_t)wr * 768 + csa * 8;

  f32x4 acc[4];
#pragma unroll
  for (int n = 0; n < 4; ++n) acc[n] = (f32x4){0.f, 0.f, 0.f, 0.f};

  kloop64(kp, 24, As, Bs, wv, frow, fsl, acc);

  const int rb = (lane >> 4) * 4;
  const int cc = lane & 15;
#pragma unroll
  for (int n = 0; n < 4; ++n) {
    const int col = bn0 + n * 16 + cc;
    if (col >= jb.N) continue;
    float bv = 0.f;
    if (jb.bias)  bv += jb.bias[col];
    if (jb.bias2) bv += jb.bias2[col];
    const int row0 = bm0 + wv * 16 + rb;
#pragma unroll
    for (int r = 0; r < 4; ++r) {
      const int row = row0 + r;
      float v = acc[n][r] + bv;
      if (jb.addend) v += jb.addend[(size_t)row * jb.ldc + col];
      if (jb.relu)   v = fmaxf(v, 0.f);
      if (jb.outf)   jb.outf[(size_t)row * jb.ldc + col] = v;
      if (jb.outh)   jb.outh[(size_t)row * jb.ldc + col] = f2h(v);
    }
  }
}

// LSTM cell, 64 rows x 16 j-cols x 4 gates (B-tile = 64 W-rows).
// W row for staged B-row r in [0,64): (r>>4)*768 + bj0 + (r&15).
// Frag n = gate n; C col cc -> j = bj0 + cc. addend = Gpre block
// (row stride 6144, gates at +0/768/1536/2304).
__device__ __forceinline__ void run_cell64(const u16* A, const u16* W,
                                           const float* bi, const float* bh_,
                                           const float* addend,
                                           const float* cprev,
                                           float* hf, float* cf, u16* hh, u16* ch,
                                           int bx, int by,
                                           u16* As, u16* Bs, int tid) {
  const int bj0 = bx * 16;
  const int bm0 = by * 64;
  const int lane = tid & 63, wv = tid >> 6;
  const int frow = lane & 15, fsl = lane >> 4;

  const int ra = tid >> 2, csa = (tid & 3) ^ SWZ(ra);
  const int wr = (ra >> 4) * 768 + bj0 + (ra & 15);

  KP64 kp;
  kp.pA = A + (size_t)(bm0 + ra) * 768 + csa * 8;
  kp.pW = W + (size_t)wr * 768 + csa * 8;

  f32x4 acc[4];
#pragma unroll
  for (int n = 0; n < 4; ++n) acc[n] = (f32x4){0.f, 0.f, 0.f, 0.f};

  kloop64(kp, 24, As, Bs, wv, frow, fsl, acc);

  const int rb = (lane >> 4) * 4;
  const int cc = lane & 15;
  const int j = bj0 + cc;
  float b_i = 0.f, b_f = 0.f, b_g = 0.f, b_o = 0.f;
  if (bi) {
    b_i = bi[j]        + bh_[j];
    b_f = bi[768 + j]  + bh_[768 + j];
    b_g = bi[1536 + j] + bh_[1536 + j];
    b_o = bi[2304 + j] + bh_[2304 + j];
  }
  const int row0 = bm0 + wv * 16 + rb;
#pragma unroll
  for (int r = 0; r < 4; ++r) {
    const int row = row0 + r;
    float gi = acc[0][r] + b_i;
    float gf = acc[1][r] + b_f;
    float gg = acc[2][r] + b_g;
    float go = acc[3][r] + b_o;
    if (addend) {
      const float* ad = addend + (size_t)row * 6144;
      gi += ad[j]; gf += ad[768 + j]; gg += ad[1536 + j]; go += ad[2304 + j];
    }
    float c = sigm(gi) * ftanh(gg);
    if (cprev) c += sigm(gf) * cprev[row * 768 + j];
    float h = sigm(go) * ftanh(c);
    if (hf) hf[row * 768 + j] = h;
    if (cf) cf[row * 768 + j] = c;
    if (hh) hh[row * 768 + j] = f2h(h);
    if (ch) ch[row * 768 + j] = f2h(c);
  }
}

__device__ __forceinline__ void cvt_seg(const float* s, u16* d, int n4,
                                        int gtid, int nthr) {
  for (int i = gtid; i < n4; i += nthr) {
    float4 v = ((const float4*)s)[i];
    ushort4 h;
    h.x = f2h(v.x); h.y = f2h(v.y); h.z = f2h(v.z); h.w = f2h(v.w);
    ((ushort4*)d)[i] = h;
  }
}

// ---------------------------------------------------------------------------
__global__ __launch_bounds__(256)
void cvt0_k(const float* x, u16* xh, const float* Wih, u16* Wihh)
{
  const int g = blockIdx.x * 256 + threadIdx.x, N = 2048 * 256;
  cvt_seg(x,   xh,   196608,  g, N);
  cvt_seg(Wih, Wihh, 1769472, g, N);
}

// K1: cell1 (0..767, 64-tiles) || Gpre task2 (768..1151, 128-tiles)
//     || cvt-rest (1152..1535)
struct K1P {
  const u16 *xh, *Wihh;
  const float *bih, *bhh;
  float *h1f, *c1f; u16* h1h;
  float* Gpre;
  const float *Whh, *hfcW, *cfcW, *midW, *o1W, *o2W, *o3W;
  u16 *Whhh, *hfch, *cfch, *midh, *o1h, *o2h, *o3h;
};

__global__ __launch_bounds__(256)
void k1_k(K1P p)
{
  __shared__ __align__(16) u16 As[8192];    // 16 KB
  __shared__ __align__(16) u16 Bs[16384];   // 32 KB
  const int blk = blockIdx.x, tid = threadIdx.x;

  if (blk < 768) {
    run_cell64(p.xh, p.Wihh, p.bih, p.bhh, nullptr, nullptr,
               p.h1f, p.c1f, p.h1h, nullptr, blk % 48, blk / 48, As, Bs, tid);
  } else if (blk < 1152) {
    const int r = blk - 768;
    GJob jb = { p.xh, p.Wihh + (size_t)3072 * 768, p.Gpre, nullptr,
                p.bih + 3072, p.bhh + 3072, nullptr, 3072, 6144, 0 };
    run_gemm128(jb, r % 24, r / 24, As, Bs, tid);
  } else {
    const int g = (blk - 1152) * 256 + tid, N = 384 * 256;
    cvt_seg(p.Whh + 2359296, p.Whhh, 1179648, g, N);   // Whh[1], Whh[2]
    cvt_seg(p.hfcW, p.hfch, 147456, g, N);
    cvt_seg(p.cfcW, p.cfch, 147456, g, N);
    cvt_seg(p.midW, p.midh, 442368, g, N);
    cvt_seg(p.o1W,  p.o1h,  38784,  g, N);
    cvt_seg(p.o2W,  p.o2h,  35136,  g, N);
    cvt_seg(p.o3W,  p.o3h,  2112,   g, N);
  }
}

// K2: cell2 (0..767, 64-tiles) || Gpre task3 (768..1151, 128-tiles)
struct K2P {
  const u16 *h1h, *Whhh, *xh, *Wihh;
  const float *Gpre_t2, *c1f, *bih, *bhh;
  float *h2f, *Gpre_t3; u16 *h2h, *c2h;
};

__global__ __launch_bounds__(256)
void k2_k(K2P p)
{
  __shared__ __align__(16) u16 As[8192];
  __shared__ __align__(16) u16 Bs[16384];
  const int blk = blockIdx.x, tid = threadIdx.x;

  if (blk < 768) {
    run_cell64(p.h1h, p.Whhh, nullptr, nullptr, p.Gpre_t2, p.c1f,
               p.h2f, nullptr, p.h2h, p.c2h, blk % 48, blk / 48, As, Bs, tid);
  } else {
    const int r = blk - 768;
    GJob jb = { p.xh, p.Wihh + (size_t)6144 * 768, p.Gpre_t3, nullptr,
                p.bih + 6144, p.bhh + 6144, nullptr, 3072, 6144, 0 };
    run_gemm128(jb, r % 24, r / 24, As, Bs, tid);
  }
}

// cell3: standalone, 64-tiles, grid (48,16)
__global__ __launch_bounds__(256)
void cell3_k(const u16* __restrict__ A, const u16* __restrict__ W,
             const float* __restrict__ addend, const float* __restrict__ cprev,
             float* hf)
{
  __shared__ __align__(16) u16 As[8192];
  __shared__ __align__(16) u16 Bs[8192];
  run_cell64(A, W, nullptr, nullptr, addend, cprev, hf, nullptr, nullptr, nullptr,
             blockIdx.x, blockIdx.y, As, Bs, threadIdx.x);
}

// z-batched 64-tile GEMMs (hfc/cfc, mid, out)
struct GArgs { GJob j[3]; };

__global__ __launch_bounds__(256)
void gemm64_k(GArgs P)
{
  __shared__ __align__(16) u16 As[8192];
  __shared__ __align__(16) u16 Bs[8192];
  run_gemm64(P.j[blockIdx.z], blockIdx.x, blockIdx.y, As, Bs, threadIdx.x);
}

// ---------------------------------------------------------------------------
// Fused attention (R8-verbatim): single pass over attn (805 MB), 3 tasks,
// coalesced lane-owns {256j + 4*lane} cols, wave-local dots, unnormalized
// exp, one end-of-kernel LDS combine.
// ---------------------------------------------------------------------------
__global__ __launch_bounds__(256)
void attn_k(const float* __restrict__ attn,
            const float* __restrict__ h1, const float* __restrict__ h2,
            const float* __restrict__ h3,
            u16* __restrict__ a1, u16* __restrict__ a2, u16* __restrict__ a3)
{
  const int b = blockIdx.x, tid = threadIdx.x;
  const int lane = tid & 63, wv = tid >> 6;
  __shared__ float accW[4][3][768];
  __shared__ float lsumW[4][3];

  const float* ab = attn + (size_t)b * 196608;
  const int cb = lane * 4;

  float4 hh[3][3];
#pragma unroll
  for (int j = 0; j < 3; ++j) {
    hh[0][j] = *(const float4*)(h1 + b * 768 + j * 256 + cb);
    hh[1][j] = *(const float4*)(h2 + b * 768 + j * 256 + cb);
    hh[2][j] = *(const float4*)(h3 + b * 768 + j * 256 + cb);
  }

  float4 acc[3][3];
#pragma unroll
  for (int t3 = 0; t3 < 3; ++t3)
#pragma unroll
    for (int j = 0; j < 3; ++j) acc[t3][j] = (float4){0.f, 0.f, 0.f, 0.f};
  float lsum[3] = {0.f, 0.f, 0.f};

  const int row0 = wv * 64;
  for (int sub = 0; sub < 16; ++sub) {
    const float* rp = ab + (size_t)(row0 + sub * 4) * 768 + cb;
    float4 vv[4][3];
#pragma unroll
    for (int s = 0; s < 4; ++s)
#pragma unroll
      for (int j = 0; j < 3; ++j)
        vv[s][j] = *(const float4*)(rp + s * 768 + j * 256);

    float q[3][4];
#pragma unroll
    for (int t3 = 0; t3 < 3; ++t3)
#pragma unroll
      for (int s = 0; s < 4; ++s) {
        float d = 0.f;
#pragma unroll
        for (int j = 0; j < 3; ++j) {
          d = fmaf(vv[s][j].x, hh[t3][j].x, d);
          d = fmaf(vv[s][j].y, hh[t3][j].y, d);
          d = fmaf(vv[s][j].z, hh[t3][j].z, d);
          d = fmaf(vv[s][j].w, hh[t3][j].w, d);
        }
        q[t3][s] = d;
      }
#pragma unroll
    for (int t3 = 0; t3 < 3; ++t3)
#pragma unroll
      for (int s = 0; s < 4; ++s) {
#pragma unroll
        for (int d = 1; d < 64; d <<= 1)
          q[t3][s] += __shfl_xor(q[t3][s], d);
        q[t3][s] = __expf(q[t3][s]);
      }
#pragma unroll
    for (int t3 = 0; t3 < 3; ++t3)
#pragma unroll
      for (int s = 0; s < 4; ++s) {
        const float pw = q[t3][s];
        lsum[t3] += pw;
#pragma unroll
        for (int j = 0; j < 3; ++j) {
          acc[t3][j].x = fmaf(pw, vv[s][j].x, acc[t3][j].x);
          acc[t3][j].y = fmaf(pw, vv[s][j].y, acc[t3][j].y);
          acc[t3][j].z = fmaf(pw, vv[s][j].z, acc[t3][j].z);
          acc[t3][j].w = fmaf(pw, vv[s][j].w, acc[t3][j].w);
        }
      }
  }

#pragma unroll
  for (int t3 = 0; t3 < 3; ++t3)
#pragma unroll
    for (int j = 0; j < 3; ++j)
      *(float4*)(&accW[wv][t3][j * 256 + cb]) = acc[t3][j];
  if (lane == 0) {
#pragma unroll
    for (int t3 = 0; t3 < 3; ++t3) lsumW[wv][t3] = lsum[t3];
  }
  __syncthreads();

  float ltot[3];
#pragma unroll
  for (int t3 = 0; t3 < 3; ++t3)
    ltot[t3] = lsumW[0][t3] + lsumW[1][t3] + lsumW[2][t3] + lsumW[3][t3];
  u16* outs[3] = { a1, a2, a3 };
#pragma unroll
  for (int cc = 0; cc < 3; ++cc) {
    const int c = tid + cc * 256;
#pragma unroll
    for (int t3 = 0; t3 < 3; ++t3) {
      float s = accW[0][t3][c] + accW[1][t3][c] + accW[2][t3][c] + accW[3][t3][c];
      outs[t3][b * 768 + c] = f2h(s / ltot[t3]);
    }
  }
}

// ---------------------------------------------------------------------------
extern "C" void kernel_launch(void* const* d_in, const int* in_sizes, int n_in,
                              void* d_out, int out_size, void* d_ws, size_t ws_size,
                              hipStream_t stream)
{
  const float* x    = (const float*)d_in[0];
  const float* attn = (const float*)d_in[1];
  const float* Wih  = (const float*)d_in[2];
  const float* Whh  = (const float*)d_in[3];
  const float* bih  = (const float*)d_in[4];
  const float* bhh  = (const float*)d_in[5];
  const float* hfcW = (const float*)d_in[6];
  const float* hfcb = (const float*)d_in[7];
  const float* cfcW = (const float*)d_in[8];
  const float* cfcb = (const float*)d_in[9];
  const float* midW = (const float*)d_in[10];
  const float* midb = (const float*)d_in[11];
  const float* o1W  = (const float*)d_in[12];
  const float* o1b  = (const float*)d_in[13];
  const float* o2W  = (const float*)d_in[14];
  const float* o2b  = (const float*)d_in[15];
  const float* o3W  = (const float*)d_in[16];
  const float* o3b  = (const float*)d_in[17];
  float* out = (float*)d_out;
  char*  ws  = (char*)d_ws;

  float* Gpre = (float*)(ws + 0);               // 1024 x 6144 fp32
  float* h1f  = (float*)(ws + 25165824);
  float* c1f  = (float*)(ws + 28311552);
  float* h2f  = (float*)(ws + 31457280);
  float* cp3f = (float*)(ws + 34603008);
  float* h3f  = (float*)(ws + 37748736);
  u16*   xh   = (u16*)(ws + 40894464);
  u16*   Wihh = (u16*)(ws + 42467328);          // all 3 tasks, 9216x768
  u16*   Whhh = (u16*)(ws + 56623104);          // Whh[1], Whh[2]
  u16*   hfch = (u16*)(ws + 66060288);
  u16*   cfch = (u16*)(ws + 67239936);
  u16*   midh = (u16*)(ws + 68419584);
  u16*   o1h  = (u16*)(ws + 71958528);
  u16*   o2h  = (u16*)(ws + 72268800);
  u16*   o3h  = (u16*)(ws + 72549888);
  u16*   h1h  = (u16*)(ws + 72566784);
  u16*   h2h  = (u16*)(ws + 74139648);
  u16*   c2h  = (u16*)(ws + 75712512);
  u16*   hp3h = (u16*)(ws + 77285376);
  u16*   a1h  = (u16*)(ws + 78858240);
  u16*   a2h  = (u16*)(ws + 80431104);
  u16*   a3h  = (u16*)(ws + 82003968);
  u16*   m1h  = (u16*)(ws + 83576832);
  u16*   m2h  = (u16*)(ws + 85149696);
  u16*   m3h  = (u16*)(ws + 86722560);
  // workspace end: 88,295,424 bytes

  // ---- K0: cvt x + Wih ----
  cvt0_k<<<2048, 256, 0, stream>>>(x, xh, Wih, Wihh);

  // ---- K1: cell1 || Gpre-task2 || cvt-rest ----
  K1P p1;
  p1.xh = xh; p1.Wihh = Wihh; p1.bih = bih; p1.bhh = bhh;
  p1.h1f = h1f; p1.c1f = c1f; p1.h1h = h1h; p1.Gpre = Gpre;
  p1.Whh = Whh; p1.hfcW = hfcW; p1.cfcW = cfcW; p1.midW = midW;
  p1.o1W = o1W; p1.o2W = o2W; p1.o3W = o3W;
  p1.Whhh = Whhh; p1.hfch = hfch; p1.cfch = cfch; p1.midh = midh;
  p1.o1h = o1h; p1.o2h = o2h; p1.o3h = o3h;
  k1_k<<<1536, 256, 0, stream>>>(p1);

  // ---- K2: cell2 || Gpre-task3 ----
  K2P p2;
  p2.h1h = h1h; p2.Whhh = Whhh; p2.xh = xh; p2.Wihh = Wihh;
  p2.Gpre_t2 = Gpre; p2.c1f = c1f; p2.bih = bih; p2.bhh = bhh;
  p2.h2f = h2f; p2.Gpre_t3 = Gpre + 3072; p2.h2h = h2h; p2.c2h = c2h;
  k2_k<<<1152, 256, 0, stream>>>(p2);

  // ---- K3: hp3 = h1 + h2*hfcW^T + hfcb ; cp3 = c1 + c2*cfcW^T + cfcb ----
  GArgs P;
  P = GArgs{};
  P.j[0] = { h2h, hfch, nullptr, hp3h, hfcb, nullptr, h1f, 768, 768, 0 };
  P.j[1] = { c2h, cfch, cp3f, nullptr, cfcb, nullptr, c1f, 768, 768, 0 };
  P.j[2] = P.j[1];
  gemm64_k<<<dim3(12, 16, 2), 256, 0, stream>>>(P);

  // ---- K4: cell3: gates = Gpre[task3] + hp3*Whh[2]^T ----
  cell3_k<<<dim3(48, 16), 256, 0, stream>>>(hp3h, Whhh + 2359296,
                                            Gpre + 3072, cp3f, h3f);

  // ---- K5: fused attention ----
  attn_k<<<1024, 256, 0, stream>>>(attn, h1f, h2f, h3f, a1h, a2h, a3h);

  // ---- K6: mid heads ----
  P = GArgs{};
  P.j[0] = { a1h, midh,           nullptr, m1h, midb,        nullptr, nullptr, 768, 768, 1 };
  P.j[1] = { a2h, midh +  589824, nullptr, m2h, midb +  768, nullptr, nullptr, 768, 768, 1 };
  P.j[2] = { a3h, midh + 1179648, nullptr, m3h, midb + 1536, nullptr, nullptr, 768, 768, 1 };
  gemm64_k<<<dim3(12, 16, 3), 256, 0, stream>>>(P);

  // ---- K7: output heads ----
  P = GArgs{};
  P.j[0] = { m1h, o1h, out,          nullptr, o1b, nullptr, nullptr, 202, 202, 0 };
  P.j[1] = { m2h, o2h, out + 206848, nullptr, o2b, nullptr, nullptr, 183, 183, 0 };
  P.j[2] = { m3h, o3h, out + 394240, nullptr, o3b, nullptr, nullptr,  11,  11, 0 };
  gemm64_k<<<dim3(4, 16, 3), 256, 0, stream>>>(P);

  (void)in_sizes; (void)n_in; (void)out_size; (void)ws_size;
}

// Round 12
// 295.612 us; speedup vs baseline: 1.1850x; 1.0454x over previous
//
#include <hip/hip_runtime.h>

// ---------------------------------------------------------------------------
// LSTMDecoder: 3 chained LSTM cells + edge FC + 3-head attention + heads.
// B=1024, H=768, S=256, C=(202,183,11).
// R12 = R11 (309us) + occupancy push on the two soft spots:
//  - attn: 2-row subtiles + launch_bounds(256,4) -> VGPR<=128 -> 4 blocks/CU
//  - Gpre on the 64-tile path -> K1/K2 uniformly 32KB LDS -> 5 blocks/CU
// fp16 MFMA, counted-vmcnt 4/2/0 64-tile pipeline everywhere, fused LSTM
// cell epilogues, fused coalesced single-pass fp32 attention. 8 nodes.
// ---------------------------------------------------------------------------

typedef unsigned short u16;
typedef _Float16       f16x8 __attribute__((ext_vector_type(8)));
typedef float          f32x4 __attribute__((ext_vector_type(4)));

#define SWZ(r) ((((r) + ((r) >> 2))) & 3)
#define VMCNT(N) asm volatile("s_waitcnt vmcnt(" #N ")" ::: "memory")
#define KBAR()  do { __builtin_amdgcn_s_barrier(); __builtin_amdgcn_sched_barrier(0); } while (0)

__device__ __forceinline__ u16 f2h(float f) {
  _Float16 h = (_Float16)f;
  return __builtin_bit_cast(u16, h);
}
__device__ __forceinline__ float sigm(float x) { return 1.f / (1.f + __expf(-x)); }
__device__ __forceinline__ float ftanh(float x) { return 1.f - 2.f / (__expf(2.f * x) + 1.f); }

__device__ __forceinline__ void gld16(const u16* g, u16* l) {
  __builtin_amdgcn_global_load_lds(
      (const __attribute__((address_space(1))) unsigned int*)(g),
      (__attribute__((address_space(3))) unsigned int*)(l),
      16, 0, 0);
}

// ======================= 64-col-N MFMA path ================================
struct KP64 { const u16 *pA, *pW; };

__device__ __forceinline__ void stage64(const KP64& kp, int kt,
                                        u16* Asb, u16* Bsb, int wv) {
  const int off = kt * 32;
  gld16(kp.pA + off, Asb + wv * 512);
  gld16(kp.pW + off, Bsb + wv * 512);
}

__device__ __forceinline__ void compute64(const u16* Asb, const u16* Bsb,
                                          int wv, int frow, int fsl, f32x4* acc) {
  const int ar = wv * 16 + frow;
  f16x8 ah = *(const f16x8*)(Asb + ar * 32 + ((fsl ^ SWZ(ar)) * 8));
  f16x8 bh[4];
#pragma unroll
  for (int n = 0; n < 4; ++n) {
    const int br = n * 16 + frow;
    bh[n] = *(const f16x8*)(Bsb + br * 32 + ((fsl ^ SWZ(br)) * 8));
  }
#pragma unroll
  for (int n = 0; n < 4; ++n)
    acc[n] = __builtin_amdgcn_mfma_f32_16x16x32_f16(ah, bh[n], acc[n], 0, 0, 0);
}

// 2 loads/thread/tile -> counted vmcnt 4/2/0; 4 buffers of 2048 u16 each side
__device__ __forceinline__ void kloop64(const KP64& kp, int NT, u16* As, u16* Bs,
                                        int wv, int frow, int fsl, f32x4* acc) {
  stage64(kp, 0, As,        Bs,        wv);
  stage64(kp, 1, As + 2048, Bs + 2048, wv);
  stage64(kp, 2, As + 4096, Bs + 4096, wv);
  for (int t = 0; t < NT - 2; ++t) {
    VMCNT(4); KBAR();
    const int cb = t & 3;
    compute64(As + cb * 2048, Bs + cb * 2048, wv, frow, fsl, acc);
    if (t + 3 < NT) {
      const int sb = (t + 3) & 3;
      stage64(kp, t + 3, As + sb * 2048, Bs + sb * 2048, wv);
    }
  }
  VMCNT(2); KBAR();
  compute64(As + ((NT - 2) & 3) * 2048, Bs + ((NT - 2) & 3) * 2048,
            wv, frow, fsl, acc);
  VMCNT(0); KBAR();
  compute64(As + ((NT - 1) & 3) * 2048, Bs + ((NT - 1) & 3) * 2048,
            wv, frow, fsl, acc);
}

struct GJob {
  const u16* A; const u16* W;
  float* outf; u16* outh;
  const float* bias; const float* bias2; const float* addend;
  int N; int ldc; int relu;
};

// plain GEMM, 64x64 tile
__device__ __forceinline__ void run_gemm64(const GJob& jb, int bx, int by,
                                           u16* As, u16* Bs, int tid) {
  const int bn0 = bx * 64;
  if (bn0 >= jb.N) return;
  const int bm0 = by * 64;
  const int lane = tid & 63, wv = tid >> 6;
  const int frow = lane & 15, fsl = lane >> 4;

  const int ra = tid >> 2, csa = (tid & 3) ^ SWZ(ra);
  int wr = bn0 + ra; if (wr >= jb.N) wr = jb.N - 1;

  KP64 kp;
  kp.pA = jb.A + (size_t)(bm0 + ra) * 768 + csa * 8;
  kp.pW = jb.W + (size_t)wr * 768 + csa * 8;

  f32x4 acc[4];
#pragma unroll
  for (int n = 0; n < 4; ++n) acc[n] = (f32x4){0.f, 0.f, 0.f, 0.f};

  kloop64(kp, 24, As, Bs, wv, frow, fsl, acc);

  const int rb = (lane >> 4) * 4;
  const int cc = lane & 15;
#pragma unroll
  for (int n = 0; n < 4; ++n) {
    const int col = bn0 + n * 16 + cc;
    if (col >= jb.N) continue;
    float bv = 0.f;
    if (jb.bias)  bv += jb.bias[col];
    if (jb.bias2) bv += jb.bias2[col];
    const int row0 = bm0 + wv * 16 + rb;
#pragma unroll
    for (int r = 0; r < 4; ++r) {
      const int row = row0 + r;
      float v = acc[n][r] + bv;
      if (jb.addend) v += jb.addend[(size_t)row * jb.ldc + col];
      if (jb.relu)   v = fmaxf(v, 0.f);
      if (jb.outf)   jb.outf[(size_t)row * jb.ldc + col] = v;
      if (jb.outh)   jb.outh[(size_t)row * jb.ldc + col] = f2h(v);
    }
  }
}

// LSTM cell, 64 rows x 16 j-cols x 4 gates (B-tile = 64 W-rows).
// W row for staged B-row r in [0,64): (r>>4)*768 + bj0 + (r&15).
__device__ __forceinline__ void run_cell64(const u16* A, const u16* W,
                                           const float* bi, const float* bh_,
                                           const float* addend,
                                           const float* cprev,
                                           float* hf, float* cf, u16* hh, u16* ch,
                                           int bx, int by,
                                           u16* As, u16* Bs, int tid) {
  const int bj0 = bx * 16;
  const int bm0 = by * 64;
  const int lane = tid & 63, wv = tid >> 6;
  const int frow = lane & 15, fsl = lane >> 4;

  const int ra = tid >> 2, csa = (tid & 3) ^ SWZ(ra);
  const int wr = (ra >> 4) * 768 + bj0 + (ra & 15);

  KP64 kp;
  kp.pA = A + (size_t)(bm0 + ra) * 768 + csa * 8;
  kp.pW = W + (size_t)wr * 768 + csa * 8;

  f32x4 acc[4];
#pragma unroll
  for (int n = 0; n < 4; ++n) acc[n] = (f32x4){0.f, 0.f, 0.f, 0.f};

  kloop64(kp, 24, As, Bs, wv, frow, fsl, acc);

  const int rb = (lane >> 4) * 4;
  const int cc = lane & 15;
  const int j = bj0 + cc;
  float b_i = 0.f, b_f = 0.f, b_g = 0.f, b_o = 0.f;
  if (bi) {
    b_i = bi[j]        + bh_[j];
    b_f = bi[768 + j]  + bh_[768 + j];
    b_g = bi[1536 + j] + bh_[1536 + j];
    b_o = bi[2304 + j] + bh_[2304 + j];
  }
  const int row0 = bm0 + wv * 16 + rb;
#pragma unroll
  for (int r = 0; r < 4; ++r) {
    const int row = row0 + r;
    float gi = acc[0][r] + b_i;
    float gf = acc[1][r] + b_f;
    float gg = acc[2][r] + b_g;
    float go = acc[3][r] + b_o;
    if (addend) {
      const float* ad = addend + (size_t)row * 6144;
      gi += ad[j]; gf += ad[768 + j]; gg += ad[1536 + j]; go += ad[2304 + j];
    }
    float c = sigm(gi) * ftanh(gg);
    if (cprev) c += sigm(gf) * cprev[row * 768 + j];
    float h = sigm(go) * ftanh(c);
    if (hf) hf[row * 768 + j] = h;
    if (cf) cf[row * 768 + j] = c;
    if (hh) hh[row * 768 + j] = f2h(h);
    if (ch) ch[row * 768 + j] = f2h(c);
  }
}

__device__ __forceinline__ void cvt_seg(const float* s, u16* d, int n4,
                                        int gtid, int nthr) {
  for (int i = gtid; i < n4; i += nthr) {
    float4 v = ((const float4*)s)[i];
    ushort4 h;
    h.x = f2h(v.x); h.y = f2h(v.y); h.z = f2h(v.z); h.w = f2h(v.w);
    ((ushort4*)d)[i] = h;
  }
}

// ---------------------------------------------------------------------------
__global__ __launch_bounds__(256)
void cvt0_k(const float* x, u16* xh, const float* Wih, u16* Wihh)
{
  const int g = blockIdx.x * 256 + threadIdx.x, N = 2048 * 256;
  cvt_seg(x,   xh,   196608,  g, N);
  cvt_seg(Wih, Wihh, 1769472, g, N);
}

// K1: cell1 (0..767) || Gpre task2 (768..1535) || cvt-rest (1536..1919)
struct K1P {
  const u16 *xh, *Wihh;
  const float *bih, *bhh;
  float *h1f, *c1f; u16* h1h;
  float* Gpre;
  const float *Whh, *hfcW, *cfcW, *midW, *o1W, *o2W, *o3W;
  u16 *Whhh, *hfch, *cfch, *midh, *o1h, *o2h, *o3h;
};

__global__ __launch_bounds__(256)
void k1_k(K1P p)
{
  __shared__ __align__(16) u16 As[8192];    // 16 KB
  __shared__ __align__(16) u16 Bs[8192];    // 16 KB -> 32 KB total, 5 blk/CU
  const int blk = blockIdx.x, tid = threadIdx.x;

  if (blk < 768) {
    run_cell64(p.xh, p.Wihh, p.bih, p.bhh, nullptr, nullptr,
               p.h1f, p.c1f, p.h1h, nullptr, blk % 48, blk / 48, As, Bs, tid);
  } else if (blk < 1536) {
    const int r = blk - 768;
    GJob jb = { p.xh, p.Wihh + (size_t)3072 * 768, p.Gpre, nullptr,
                p.bih + 3072, p.bhh + 3072, nullptr, 3072, 6144, 0 };
    run_gemm64(jb, r % 48, r / 48, As, Bs, tid);
  } else {
    const int g = (blk - 1536) * 256 + tid, N = 384 * 256;
    cvt_seg(p.Whh + 2359296, p.Whhh, 1179648, g, N);   // Whh[1], Whh[2]
    cvt_seg(p.hfcW, p.hfch, 147456, g, N);
    cvt_seg(p.cfcW, p.cfch, 147456, g, N);
    cvt_seg(p.midW, p.midh, 442368, g, N);
    cvt_seg(p.o1W,  p.o1h,  38784,  g, N);
    cvt_seg(p.o2W,  p.o2h,  35136,  g, N);
    cvt_seg(p.o3W,  p.o3h,  2112,   g, N);
  }
}

// K2: cell2 (0..767) || Gpre task3 (768..1535)
struct K2P {
  const u16 *h1h, *Whhh, *xh, *Wihh;
  const float *Gpre_t2, *c1f, *bih, *bhh;
  float *h2f, *Gpre_t3; u16 *h2h, *c2h;
};

__global__ __launch_bounds__(256)
void k2_k(K2P p)
{
  __shared__ __align__(16) u16 As[8192];
  __shared__ __align__(16) u16 Bs[8192];
  const int blk = blockIdx.x, tid = threadIdx.x;

  if (blk < 768) {
    run_cell64(p.h1h, p.Whhh, nullptr, nullptr, p.Gpre_t2, p.c1f,
               p.h2f, nullptr, p.h2h, p.c2h, blk % 48, blk / 48, As, Bs, tid);
  } else {
    const int r = blk - 768;
    GJob jb = { p.xh, p.Wihh + (size_t)6144 * 768, p.Gpre_t3, nullptr,
                p.bih + 6144, p.bhh + 6144, nullptr, 3072, 6144, 0 };
    run_gemm64(jb, r % 48, r / 48, As, Bs, tid);
  }
}

// cell3: standalone, 64-tiles, grid (48,16)
__global__ __launch_bounds__(256)
void cell3_k(const u16* __restrict__ A, const u16* __restrict__ W,
             const float* __restrict__ addend, const float* __restrict__ cprev,
             float* hf)
{
  __shared__ __align__(16) u16 As[8192];
  __shared__ __align__(16) u16 Bs[8192];
  run_cell64(A, W, nullptr, nullptr, addend, cprev, hf, nullptr, nullptr, nullptr,
             blockIdx.x, blockIdx.y, As, Bs, threadIdx.x);
}

// z-batched 64-tile GEMMs (hfc/cfc, mid, out)
struct GArgs { GJob j[3]; };

__global__ __launch_bounds__(256)
void gemm64_k(GArgs P)
{
  __shared__ __align__(16) u16 As[8192];
  __shared__ __align__(16) u16 Bs[8192];
  run_gemm64(P.j[blockIdx.z], blockIdx.x, blockIdx.y, As, Bs, threadIdx.x);
}

// ---------------------------------------------------------------------------
// Fused attention: single pass over attn (805 MB), 3 tasks, coalesced
// lane-owns {256j + 4*lane} cols, wave-local dots, unnormalized exp, one
// end-of-kernel LDS combine. R12: 2-row subtiles + launch_bounds(256,4)
// -> VGPR<=128 -> 4 blocks/CU (was ~3) for deeper BW latency hiding.
// ---------------------------------------------------------------------------
__global__ __launch_bounds__(256, 4)
void attn_k(const float* __restrict__ attn,
            const float* __restrict__ h1, const float* __restrict__ h2,
            const float* __restrict__ h3,
            u16* __restrict__ a1, u16* __restrict__ a2, u16* __restrict__ a3)
{
  const int b = blockIdx.x, tid = threadIdx.x;
  const int lane = tid & 63, wv = tid >> 6;
  __shared__ float accW[4][3][768];
  __shared__ float lsumW[4][3];

  const float* ab = attn + (size_t)b * 196608;
  const int cb = lane * 4;

  float4 hh[3][3];
#pragma unroll
  for (int j = 0; j < 3; ++j) {
    hh[0][j] = *(const float4*)(h1 + b * 768 + j * 256 + cb);
    hh[1][j] = *(const float4*)(h2 + b * 768 + j * 256 + cb);
    hh[2][j] = *(const float4*)(h3 + b * 768 + j * 256 + cb);
  }

  float4 acc[3][3];
#pragma unroll
  for (int t3 = 0; t3 < 3; ++t3)
#pragma unroll
    for (int j = 0; j < 3; ++j) acc[t3][j] = (float4){0.f, 0.f, 0.f, 0.f};
  float lsum[3] = {0.f, 0.f, 0.f};

  const int row0 = wv * 64;
  for (int sub = 0; sub < 32; ++sub) {
    const float* rp = ab + (size_t)(row0 + sub * 2) * 768 + cb;
    float4 vv[2][3];
#pragma unroll
    for (int s = 0; s < 2; ++s)
#pragma unroll
      for (int j = 0; j < 3; ++j)
        vv[s][j] = *(const float4*)(rp + s * 768 + j * 256);

    float q[3][2];
#pragma unroll
    for (int t3 = 0; t3 < 3; ++t3)
#pragma unroll
      for (int s = 0; s < 2; ++s) {
        float d = 0.f;
#pragma unroll
        for (int j = 0; j < 3; ++j) {
          d = fmaf(vv[s][j].x, hh[t3][j].x, d);
          d = fmaf(vv[s][j].y, hh[t3][j].y, d);
          d = fmaf(vv[s][j].z, hh[t3][j].z, d);
          d = fmaf(vv[s][j].w, hh[t3][j].w, d);
        }
        q[t3][s] = d;
      }
#pragma unroll
    for (int t3 = 0; t3 < 3; ++t3)
#pragma unroll
      for (int s = 0; s < 2; ++s) {
#pragma unroll
        for (int d = 1; d < 64; d <<= 1)
          q[t3][s] += __shfl_xor(q[t3][s], d);
        q[t3][s] = __expf(q[t3][s]);
      }
#pragma unroll
    for (int t3 = 0; t3 < 3; ++t3)
#pragma unroll
      for (int s = 0; s < 2; ++s) {
        const float pw = q[t3][s];
        lsum[t3] += pw;
#pragma unroll
        for (int j = 0; j < 3; ++j) {
          acc[t3][j].x = fmaf(pw, vv[s][j].x, acc[t3][j].x);
          acc[t3][j].y = fmaf(pw, vv[s][j].y, acc[t3][j].y);
          acc[t3][j].z = fmaf(pw, vv[s][j].z, acc[t3][j].z);
          acc[t3][j].w = fmaf(pw, vv[s][j].w, acc[t3][j].w);
        }
      }
  }

#pragma unroll
  for (int t3 = 0; t3 < 3; ++t3)
#pragma unroll
    for (int j = 0; j < 3; ++j)
      *(float4*)(&accW[wv][t3][j * 256 + cb]) = acc[t3][j];
  if (lane == 0) {
#pragma unroll
    for (int t3 = 0; t3 < 3; ++t3) lsumW[wv][t3] = lsum[t3];
  }
  __syncthreads();

  float ltot[3];
#pragma unroll
  for (int t3 = 0; t3 < 3; ++t3)
    ltot[t3] = lsumW[0][t3] + lsumW[1][t3] + lsumW[2][t3] + lsumW[3][t3];
  u16* outs[3] = { a1, a2, a3 };
#pragma unroll
  for (int cc = 0; cc < 3; ++cc) {
    const int c = tid + cc * 256;
#pragma unroll
    for (int t3 = 0; t3 < 3; ++t3) {
      float s = accW[0][t3][c] + accW[1][t3][c] + accW[2][t3][c] + accW[3][t3][c];
      outs[t3][b * 768 + c] = f2h(s / ltot[t3]);
    }
  }
}

// ---------------------------------------------------------------------------
extern "C" void kernel_launch(void* const* d_in, const int* in_sizes, int n_in,
                              void* d_out, int out_size, void* d_ws, size_t ws_size,
                              hipStream_t stream)
{
  const float* x    = (const float*)d_in[0];
  const float* attn = (const float*)d_in[1];
  const float* Wih  = (const float*)d_in[2];
  const float* Whh  = (const float*)d_in[3];
  const float* bih  = (const float*)d_in[4];
  const float* bhh  = (const float*)d_in[5];
  const float* hfcW = (const float*)d_in[6];
  const float* hfcb = (const float*)d_in[7];
  const float* cfcW = (const float*)d_in[8];
  const float* cfcb = (const float*)d_in[9];
  const float* midW = (const float*)d_in[10];
  const float* midb = (const float*)d_in[11];
  const float* o1W  = (const float*)d_in[12];
  const float* o1b  = (const float*)d_in[13];
  const float* o2W  = (const float*)d_in[14];
  const float* o2b  = (const float*)d_in[15];
  const float* o3W  = (const float*)d_in[16];
  const float* o3b  = (const float*)d_in[17];
  float* out = (float*)d_out;
  char*  ws  = (char*)d_ws;

  float* Gpre = (float*)(ws + 0);               // 1024 x 6144 fp32
  float* h1f  = (float*)(ws + 25165824);
  float* c1f  = (float*)(ws + 28311552);
  float* h2f  = (float*)(ws + 31457280);
  float* cp3f = (float*)(ws + 34603008);
  float* h3f  = (float*)(ws + 37748736);
  u16*   xh   = (u16*)(ws + 40894464);
  u16*   Wihh = (u16*)(ws + 42467328);          // all 3 tasks, 9216x768
  u16*   Whhh = (u16*)(ws + 56623104);          // Whh[1], Whh[2]
  u16*   hfch = (u16*)(ws + 66060288);
  u16*   cfch = (u16*)(ws + 67239936);
  u16*   midh = (u16*)(ws + 68419584);
  u16*   o1h  = (u16*)(ws + 71958528);
  u16*   o2h  = (u16*)(ws + 72268800);
  u16*   o3h  = (u16*)(ws + 72549888);
  u16*   h1h  = (u16*)(ws + 72566784);
  u16*   h2h  = (u16*)(ws + 74139648);
  u16*   c2h  = (u16*)(ws + 75712512);
  u16*   hp3h = (u16*)(ws + 77285376);
  u16*   a1h  = (u16*)(ws + 78858240);
  u16*   a2h  = (u16*)(ws + 80431104);
  u16*   a3h  = (u16*)(ws + 82003968);
  u16*   m1h  = (u16*)(ws + 83576832);
  u16*   m2h  = (u16*)(ws + 85149696);
  u16*   m3h  = (u16*)(ws + 86722560);
  // workspace end: 88,295,424 bytes

  // ---- K0: cvt x + Wih ----
  cvt0_k<<<2048, 256, 0, stream>>>(x, xh, Wih, Wihh);

  // ---- K1: cell1 || Gpre-task2 || cvt-rest ----
  K1P p1;
  p1.xh = xh; p1.Wihh = Wihh; p1.bih = bih; p1.bhh = bhh;
  p1.h1f = h1f; p1.c1f = c1f; p1.h1h = h1h; p1.Gpre = Gpre;
  p1.Whh = Whh; p1.hfcW = hfcW; p1.cfcW = cfcW; p1.midW = midW;
  p1.o1W = o1W; p1.o2W = o2W; p1.o3W = o3W;
  p1.Whhh = Whhh; p1.hfch = hfch; p1.cfch = cfch; p1.midh = midh;
  p1.o1h = o1h; p1.o2h = o2h; p1.o3h = o3h;
  k1_k<<<1920, 256, 0, stream>>>(p1);

  // ---- K2: cell2 || Gpre-task3 ----
  K2P p2;
  p2.h1h = h1h; p2.Whhh = Whhh; p2.xh = xh; p2.Wihh = Wihh;
  p2.Gpre_t2 = Gpre; p2.c1f = c1f; p2.bih = bih; p2.bhh = bhh;
  p2.h2f = h2f; p2.Gpre_t3 = Gpre + 3072; p2.h2h = h2h; p2.c2h = c2h;
  k2_k<<<1536, 256, 0, stream>>>(p2);

  // ---- K3: hp3 = h1 + h2*hfcW^T + hfcb ; cp3 = c1 + c2*cfcW^T + cfcb ----
  GArgs P;
  P = GArgs{};
  P.j[0] = { h2h, hfch, nullptr, hp3h, hfcb, nullptr, h1f, 768, 768, 0 };
  P.j[1] = { c2h, cfch, cp3f, nullptr, cfcb, nullptr, c1f, 768, 768, 0 };
  P.j[2] = P.j[1];
  gemm64_k<<<dim3(12, 16, 2), 256, 0, stream>>>(P);

  // ---- K4: cell3: gates = Gpre[task3] + hp3*Whh[2]^T ----
  cell3_k<<<dim3(48, 16), 256, 0, stream>>>(hp3h, Whhh + 2359296,
                                            Gpre + 3072, cp3f, h3f);

  // ---- K5: fused attention ----
  attn_k<<<1024, 256, 0, stream>>>(attn, h1f, h2f, h3f, a1h, a2h, a3h);

  // ---- K6: mid heads ----
  P = GArgs{};
  P.j[0] = { a1h, midh,           nullptr, m1h, midb,        nullptr, nullptr, 768, 768, 1 };
  P.j[1] = { a2h, midh +  589824, nullptr, m2h, midb +  768, nullptr, nullptr, 768, 768, 1 };
  P.j[2] = { a3h, midh + 1179648, nullptr, m3h, midb + 1536, nullptr, nullptr, 768, 768, 1 };
  gemm64_k<<<dim3(12, 16, 3), 256, 0, stream>>>(P);

  // ---- K7: output heads ----
  P = GArgs{};
  P.j[0] = { m1h, o1h, out,          nullptr, o1b, nullptr, nullptr, 202, 202, 0 };
  P.j[1] = { m2h, o2h, out + 206848, nullptr, o2b, nullptr, nullptr, 183, 183, 0 };
  P.j[2] = { m3h, o3h, out + 394240, nullptr, o3b, nullptr, nullptr,  11,  11, 0 };
  gemm64_k<<<dim3(4, 16, 3), 256, 0, stream>>>(P);

  (void)in_sizes; (void)n_in; (void)out_size; (void)ws_size;
}